// Round 4
// baseline (1011.123 us; speedup 1.0000x reference)
//
#include <hip/hip_runtime.h>
#include <cstdint>
#include <cstddef>

#define NODES  100000
#define EDGES  3200000
#define FIN    128
#define HIDDEN 256
#define EMBD   128
#define GRAPHS 2048

typedef _Float16 f16;
typedef f16 f16x2 __attribute__((ext_vector_type(2)));
typedef f16 f16x4 __attribute__((ext_vector_type(4)));
typedef f16 f16x8 __attribute__((ext_vector_type(8)));
typedef float f32x4 __attribute__((ext_vector_type(4)));

// ---------------- CSR build ----------------
__global__ void hist_k(const int* __restrict__ dst, int* __restrict__ cnt) {
  int stride = gridDim.x * blockDim.x;
  for (int i = blockIdx.x * blockDim.x + threadIdx.x; i < EDGES; i += stride)
    atomicAdd(&cnt[dst[i]], 1);
}

__global__ void scan1_k(const int* __restrict__ cnt, int* __restrict__ row_ptr,
                        int* __restrict__ bsum) {
  __shared__ int sh[256];
  int i = blockIdx.x * 256 + threadIdx.x;
  int v = (i < NODES) ? cnt[i] : 0;
  sh[threadIdx.x] = v;
  __syncthreads();
  for (int off = 1; off < 256; off <<= 1) {
    int t = (threadIdx.x >= off) ? sh[threadIdx.x - off] : 0;
    __syncthreads();
    sh[threadIdx.x] += t;
    __syncthreads();
  }
  if (i < NODES) row_ptr[i + 1] = sh[threadIdx.x];
  if (threadIdx.x == 255) bsum[blockIdx.x] = sh[255];
}

__global__ void scan2_k(int* __restrict__ bsum, int nb) {
  __shared__ int sh[512];
  int v = (threadIdx.x < nb) ? bsum[threadIdx.x] : 0;
  sh[threadIdx.x] = v;
  __syncthreads();
  for (int off = 1; off < 512; off <<= 1) {
    int t = (threadIdx.x >= off) ? sh[threadIdx.x - off] : 0;
    __syncthreads();
    sh[threadIdx.x] += t;
    __syncthreads();
  }
  if (threadIdx.x < nb) bsum[threadIdx.x] = sh[threadIdx.x] - v;  // exclusive
}

__global__ void scan3_k(const int* __restrict__ cnt, const int* __restrict__ bsum,
                        int* __restrict__ row_ptr, float* __restrict__ dinv,
                        int* __restrict__ cursor) {
  int i = blockIdx.x * 256 + threadIdx.x;
  if (i >= NODES) return;
  row_ptr[i + 1] += bsum[blockIdx.x];
  dinv[i] = rsqrtf((float)(cnt[i] + 1));
  cursor[i] = 0;
  if (i == 0) row_ptr[0] = 0;
}

// Range-partitioned fill: only edges with dst in [lo,hi) are written this pass,
// confining the random 4B scatter to a ~3.2MB csr region that stays L2-resident
// until lines are densely filled (kills the 16x write amplification).
__global__ void fillp_k(const int* __restrict__ src, const int* __restrict__ dst,
                        const int* __restrict__ row_ptr, int* __restrict__ cursor,
                        int* __restrict__ csr_src, int lo, int hi) {
  int stride = gridDim.x * blockDim.x;
  for (int i = blockIdx.x * blockDim.x + threadIdx.x; i < EDGES; i += stride) {
    int d = dst[i];
    if (d >= lo && d < hi) {
      int pos = row_ptr[d] + atomicAdd(&cursor[d], 1);
      csr_src[pos] = src[i];
    }
  }
}

// ---------------- prescale: xs[i] = f16(dinv[i] * x[i]) ----------------
__global__ void prescale_k(const float* __restrict__ x, const float* __restrict__ dinv,
                           f16* __restrict__ xs) {
  int idx = blockIdx.x * blockDim.x + threadIdx.x;  // over NODES*FIN/4
  if (idx >= NODES * FIN / 4) return;
  int row = idx >> 5;  // FIN/4 = 32 float4 per row
  float4 v = *(const float4*)(x + (size_t)idx * 4);
  float d = dinv[row];
  f16x4 o = {(f16)(d * v.x), (f16)(d * v.y), (f16)(d * v.z), (f16)(d * v.w)};
  *(f16x4*)(xs + (size_t)idx * 4) = o;
}

// ---------------- weight convert+transpose: Wt[m][k] = f16(W[k][m]) ----------------
__global__ void convw_k(const float* __restrict__ W, f16* __restrict__ Wt, int K, int M) {
  int i = blockIdx.x * blockDim.x + threadIdx.x;
  if (i >= K * M) return;
  int k = i / M, m = i - k * M;
  Wt[(size_t)m * K + k] = (f16)W[i];
}

// ---------------- aggregation (f16 in, fp32 accum), 16-deep MLP unroll ----------------
// in is dinv-prescaled: out[i] = dinv[i] * (sum_{s in N(i)} in[s] + in[i]) (+bias, FINAL->fp32)
template <int V, bool FINAL>
__global__ __launch_bounds__(256) void agg_h(const f16* __restrict__ in, void* __restrict__ outv,
                      const int* __restrict__ row_ptr, const int* __restrict__ csr_src,
                      const float* __restrict__ dinv, const float* __restrict__ bias) {
  constexpr int D = V * 64;
  constexpr int U = 16;  // gathers kept in flight
  int node = (blockIdx.x * blockDim.x + threadIdx.x) >> 6;
  int lane = threadIdx.x & 63;
  if (node >= NODES) return;
  const int c0 = lane * V;
  const f16* __restrict__ inc = in + c0;

  float acc[V];
#pragma unroll
  for (int v = 0; v < V; ++v) acc[v] = 0.f;

  int beg = row_ptr[node], end = row_ptr[node + 1];
  int k = beg;
  for (; k + U <= end; k += U) {
    int s[U];
#pragma unroll
    for (int u = 0; u < U; ++u) s[u] = csr_src[k + u];
    if (V == 4) {
      f16x4 hv[U];
#pragma unroll
      for (int u = 0; u < U; ++u) hv[u] = *(const f16x4*)(inc + (size_t)s[u] * D);
#pragma unroll
      for (int u = 0; u < U; ++u) {
        acc[0] += (float)hv[u][0]; acc[1] += (float)hv[u][1];
        acc[2] += (float)hv[u][2]; acc[3] += (float)hv[u][3];
      }
    } else {
      f16x2 hv[U];
#pragma unroll
      for (int u = 0; u < U; ++u) hv[u] = *(const f16x2*)(inc + (size_t)s[u] * D);
#pragma unroll
      for (int u = 0; u < U; ++u) {
        acc[0] += (float)hv[u][0]; acc[1] += (float)hv[u][1];
      }
    }
  }
  // tail
  for (; k < end; ++k) {
    int s = csr_src[k];
    if (V == 4) {
      f16x4 hv = *(const f16x4*)(inc + (size_t)s * D);
      acc[0] += (float)hv[0]; acc[1] += (float)hv[1];
      acc[2] += (float)hv[2]; acc[3] += (float)hv[3];
    } else {
      f16x2 hv = *(const f16x2*)(inc + (size_t)s * D);
      acc[0] += (float)hv[0]; acc[1] += (float)hv[1];
    }
  }
  // self-loop term
  if (V == 4) {
    f16x4 hv = *(const f16x4*)(inc + (size_t)node * D);
    acc[0] += (float)hv[0]; acc[1] += (float)hv[1];
    acc[2] += (float)hv[2]; acc[3] += (float)hv[3];
  } else {
    f16x2 hv = *(const f16x2*)(inc + (size_t)node * D);
    acc[0] += (float)hv[0]; acc[1] += (float)hv[1];
  }

  float di = dinv[node];
  if (FINAL) {
    float* out = (float*)outv;
    if (V == 4) {
      float4 o = {di * acc[0] + bias[c0], di * acc[1] + bias[c0 + 1],
                  di * acc[2] + bias[c0 + 2], di * acc[3] + bias[c0 + 3]};
      *(float4*)(out + (size_t)node * D + c0) = o;
    } else {
      float2 o = {di * acc[0] + bias[c0], di * acc[1] + bias[c0 + 1]};
      *(float2*)(out + (size_t)node * D + c0) = o;
    }
  } else {
    f16* out = (f16*)outv;
    if (V == 4) {
      f16x4 o = {(f16)(di * acc[0]), (f16)(di * acc[1]),
                 (f16)(di * acc[2]), (f16)(di * acc[3])};
      *(f16x4*)(out + (size_t)node * D + c0) = o;
    } else {
      f16x2 o = {(f16)(di * acc[0]), (f16)(di * acc[1])};
      *(f16x2*)(out + (size_t)node * D + c0) = o;
    }
  }
}

// ---------------- f16 MFMA GEMM: C[N,M] = epi(A[N,K] @ W[K,M]) ----------------
template <int K, bool RELU, bool BIAS, bool DSCALE>
__global__ __launch_bounds__(256) void gemm_h(const f16* __restrict__ A,
                                              const f16* __restrict__ Wt,
                                              const float* __restrict__ bias,
                                              const float* __restrict__ dinv,
                                              f16* __restrict__ C, int N, int M) {
  __shared__ f16 As[128][40];  // [row][k], pad to 40 halves (80B) for bank spread
  __shared__ f16 Bs[128][40];  // [col][k]

  const int tid = threadIdx.x;
  const int rowbase = blockIdx.x * 128;
  const int colbase = blockIdx.y * 128;
  const int l = tid & 63;
  const int wr = ((tid >> 6) >> 1) * 64;  // wave row offset 0/64
  const int wc = ((tid >> 6) & 1) * 64;   // wave col offset 0/64
  const int lr = tid >> 1;                // 0..127: tile row (A) / tile col (B)
  const int lc = (tid & 1) * 16;          // half-offset within BK=32

  f32x4 acc[4][4];
#pragma unroll
  for (int i = 0; i < 4; ++i)
#pragma unroll
    for (int j = 0; j < 4; ++j) acc[i][j] = (f32x4){0.f, 0.f, 0.f, 0.f};

  const int arow = min(rowbase + lr, N - 1);  // clamp: OOB rows read row N-1, never stored
  const f16* aptr = A + (size_t)arow * K + lc;
  const f16* bptr = Wt + (size_t)(colbase + lr) * K + lc;

  for (int kb = 0; kb < K; kb += 32) {
    *(f16x8*)&As[lr][lc]     = *(const f16x8*)(aptr + kb);
    *(f16x8*)&As[lr][lc + 8] = *(const f16x8*)(aptr + kb + 8);
    *(f16x8*)&Bs[lr][lc]     = *(const f16x8*)(bptr + kb);
    *(f16x8*)&Bs[lr][lc + 8] = *(const f16x8*)(bptr + kb + 8);
    __syncthreads();

    f16x8 a[4], b[4];
#pragma unroll
    for (int f = 0; f < 4; ++f) {
      a[f] = *(const f16x8*)&As[wr + f * 16 + (l & 15)][(l >> 4) * 8];
      b[f] = *(const f16x8*)&Bs[wc + f * 16 + (l & 15)][(l >> 4) * 8];
    }
#pragma unroll
    for (int fm = 0; fm < 4; ++fm)
#pragma unroll
      for (int fn = 0; fn < 4; ++fn)
        acc[fm][fn] = __builtin_amdgcn_mfma_f32_16x16x32_f16(a[fm], b[fn], acc[fm][fn], 0, 0, 0);
    __syncthreads();
  }

  float bv[4];
#pragma unroll
  for (int fn = 0; fn < 4; ++fn)
    bv[fn] = BIAS ? bias[colbase + wc + fn * 16 + (l & 15)] : 0.f;

#pragma unroll
  for (int fm = 0; fm < 4; ++fm) {
#pragma unroll
    for (int r = 0; r < 4; ++r) {
      int row = rowbase + wr + fm * 16 + (l >> 4) * 4 + r;
      if (row >= N) continue;
      float dv = DSCALE ? dinv[row] : 1.f;
#pragma unroll
      for (int fn = 0; fn < 4; ++fn) {
        int col = colbase + wc + fn * 16 + (l & 15);
        float v = acc[fm][fn][r] + bv[fn];
        if (RELU) v = fmaxf(v, 0.f);
        C[(size_t)row * M + col] = (f16)(v * dv);
      }
    }
  }
}

// ---------------- fp32 GEMM for the tiny head (N=2048) ----------------
template <int K, bool RELU, bool HAS_BIAS>
__global__ __launch_bounds__(256) void gemm_k(const float* __restrict__ A,
                                              const float* __restrict__ W,
                                              const float* __restrict__ bias,
                                              float* __restrict__ C, int N, int M) {
  constexpr int KB = 16;
  __shared__ float As[KB][128];
  __shared__ float Ws[KB][128];

  const int tid = threadIdx.x;
  const int rowbase = blockIdx.x * 128;
  const int colbase = blockIdx.y * 128;
  const int tr = tid >> 4;
  const int tc = tid & 15;
  const int ar = tid >> 1;
  const int ac4_0 = (tid & 1) * 2;
  const int wk = tid >> 4;
  const int wc4_0 = (tid & 15) * 2;

  float acc[8][8];
#pragma unroll
  for (int i = 0; i < 8; ++i)
#pragma unroll
    for (int j = 0; j < 8; ++j) acc[i][j] = 0.f;

  for (int kb = 0; kb < K; kb += KB) {
#pragma unroll
    for (int q = 0; q < 2; ++q) {
      int c4 = ac4_0 + q;
      int grow = rowbase + ar;
      float4 v = make_float4(0.f, 0.f, 0.f, 0.f);
      if (grow < N) v = *(const float4*)(A + (size_t)grow * K + kb + c4 * 4);
      As[c4 * 4 + 0][ar] = v.x;
      As[c4 * 4 + 1][ar] = v.y;
      As[c4 * 4 + 2][ar] = v.z;
      As[c4 * 4 + 3][ar] = v.w;
    }
#pragma unroll
    for (int q = 0; q < 2; ++q) {
      int c4 = wc4_0 + q;
      float4 v = *(const float4*)(W + (size_t)(kb + wk) * M + colbase + c4 * 4);
      *(float4*)&Ws[wk][c4 * 4] = v;
    }
    __syncthreads();

#pragma unroll
    for (int kk = 0; kk < KB; ++kk) {
      float4 a0 = *(const float4*)&As[kk][tr * 4];
      float4 a1 = *(const float4*)&As[kk][tr * 4 + 64];
      float4 w0 = *(const float4*)&Ws[kk][tc * 4];
      float4 w1 = *(const float4*)&Ws[kk][tc * 4 + 64];
      float a[8] = {a0.x, a0.y, a0.z, a0.w, a1.x, a1.y, a1.z, a1.w};
      float w[8] = {w0.x, w0.y, w0.z, w0.w, w1.x, w1.y, w1.z, w1.w};
#pragma unroll
      for (int i = 0; i < 8; ++i)
#pragma unroll
        for (int j = 0; j < 8; ++j) acc[i][j] = fmaf(a[i], w[j], acc[i][j]);
    }
    __syncthreads();
  }

#pragma unroll
  for (int i = 0; i < 8; ++i) {
    int r = rowbase + ((i < 4) ? (tr * 4 + i) : (64 + tr * 4 + (i - 4)));
    if (r >= N) continue;
#pragma unroll
    for (int jh = 0; jh < 2; ++jh) {
      int c = colbase + tc * 4 + jh * 64;
      float4 o;
      o.x = acc[i][jh * 4 + 0];
      o.y = acc[i][jh * 4 + 1];
      o.z = acc[i][jh * 4 + 2];
      o.w = acc[i][jh * 4 + 3];
      if (HAS_BIAS) {
        o.x += bias[c]; o.y += bias[c + 1]; o.z += bias[c + 2]; o.w += bias[c + 3];
      }
      if (RELU) {
        o.x = fmaxf(o.x, 0.f); o.y = fmaxf(o.y, 0.f);
        o.z = fmaxf(o.z, 0.f); o.w = fmaxf(o.w, 0.f);
      }
      *(float4*)(C + (size_t)r * M + c) = o;
    }
  }
}

// ---------------- mean pooling per graph (batch sorted) ----------------
__global__ void pool_k(const float* __restrict__ h, const int* __restrict__ batch,
                       float* __restrict__ pooled) {
  int g = blockIdx.x;
  int j = threadIdx.x;  // 128 threads = EMBD
  int lo = 0, hi = NODES;
  while (lo < hi) { int mid = (lo + hi) >> 1; if (batch[mid] < g) lo = mid + 1; else hi = mid; }
  int start = lo;
  int lo2 = start, hi2 = NODES;
  while (lo2 < hi2) { int mid = (lo2 + hi2) >> 1; if (batch[mid] < g + 1) lo2 = mid + 1; else hi2 = mid; }
  int end = lo2;
  float s = 0.f;
  for (int r = start; r < end; ++r) s += h[(size_t)r * EMBD + j];
  float c = (float)(end - start);
  pooled[g * EMBD + j] = s / fmaxf(c, 1.f);
}

// ---------------- head: logits = z2 @ Wc3[128,2] + bc3 ----------------
__global__ void head_k(const float* __restrict__ z2, const float* __restrict__ Wc3,
                       const float* __restrict__ bc3, float* __restrict__ out) {
  int wv = (blockIdx.x * blockDim.x + threadIdx.x) >> 6;
  int lane = threadIdx.x & 63;
  if (wv >= GRAPHS) return;
  float2 z = *(const float2*)(z2 + (size_t)wv * 128 + lane * 2);
  int j0 = lane * 2;
  float a0 = z.x * Wc3[j0 * 2 + 0] + z.y * Wc3[(j0 + 1) * 2 + 0];
  float a1 = z.x * Wc3[j0 * 2 + 1] + z.y * Wc3[(j0 + 1) * 2 + 1];
  for (int off = 32; off; off >>= 1) {
    a0 += __shfl_down(a0, off);
    a1 += __shfl_down(a1, off);
  }
  if (lane == 0) {
    out[wv * 2 + 0] = a0 + bc3[0];
    out[wv * 2 + 1] = a1 + bc3[1];
  }
}

extern "C" void kernel_launch(void* const* d_in, const int* in_sizes, int n_in,
                              void* d_out, int out_size, void* d_ws, size_t ws_size,
                              hipStream_t stream) {
  const float* x    = (const float*)d_in[0];
  const int*   ei   = (const int*)d_in[1];
  const int*   batch= (const int*)d_in[2];
  const float* W1 = (const float*)d_in[3];  const float* b1 = (const float*)d_in[4];
  const float* W2 = (const float*)d_in[5];  const float* b2 = (const float*)d_in[6];
  const float* W3 = (const float*)d_in[7];  const float* b3 = (const float*)d_in[8];
  const float* Wc1= (const float*)d_in[9];  const float* bc1= (const float*)d_in[10];
  const float* Wc2= (const float*)d_in[11]; const float* bc2= (const float*)d_in[12];
  const float* Wc3= (const float*)d_in[13]; const float* bc3= (const float*)d_in[14];
  float* out = (float*)d_out;

  char* ws = (char*)d_ws;
  size_t off = 0;
  auto alloc = [&](size_t bytes) -> void* {
    void* p = ws + off;
    off = (off + bytes + 255) & ~(size_t)255;
    return p;
  };
  f16*   F0      = (f16*)alloc((size_t)NODES * 256 * 2);
  f16*   F1      = (f16*)alloc((size_t)NODES * 256 * 2);
  float* R0      = (float*)alloc((size_t)NODES * 128 * 4);
  int*   csr_src = (int*)alloc((size_t)EDGES * 4);
  int*   row_ptr = (int*)alloc((size_t)(NODES + 1) * 4);
  int*   cnt     = (int*)alloc((size_t)NODES * 4);
  int*   cursor  = (int*)alloc((size_t)NODES * 4);
  float* dinv    = (float*)alloc((size_t)NODES * 4);
  int*   bsum    = (int*)alloc(512 * 4);
  f16*   Wt1     = (f16*)alloc((size_t)FIN * HIDDEN * 2);
  f16*   Wt2     = (f16*)alloc((size_t)HIDDEN * HIDDEN * 2);
  f16*   Wt3     = (f16*)alloc((size_t)HIDDEN * EMBD * 2);
  // fp32 overlays in F0 (dead after GEMM3 consumed it -> reused post-agg3)
  float* pooled = (float*)F0;
  float* z1     = pooled + (size_t)GRAPHS * EMBD;
  float* z2     = z1 + (size_t)GRAPHS * HIDDEN;

  const int* srcA = ei;
  const int* dstA = ei + EDGES;

  const int nb = (NODES + 255) / 256;  // 391
  hipMemsetAsync(cnt, 0, (size_t)NODES * 4, stream);
  hist_k<<<2048, 256, 0, stream>>>(dstA, cnt);
  scan1_k<<<nb, 256, 0, stream>>>(cnt, row_ptr, bsum);
  scan2_k<<<1, 512, 0, stream>>>(bsum, nb);
  scan3_k<<<nb, 256, 0, stream>>>(cnt, bsum, row_ptr, dinv, cursor);
  // 4-pass range-partitioned fill: each pass's write region (~3.2MB) is L2-resident
  {
    const int Q = (NODES + 3) / 4;
    for (int p = 0; p < 4; ++p)
      fillp_k<<<2048, 256, 0, stream>>>(srcA, dstA, row_ptr, cursor, csr_src,
                                        p * Q, min((p + 1) * Q, NODES));
  }

  convw_k<<<(FIN * HIDDEN + 255) / 256, 256, 0, stream>>>(W1, Wt1, FIN, HIDDEN);
  convw_k<<<(HIDDEN * HIDDEN + 255) / 256, 256, 0, stream>>>(W2, Wt2, HIDDEN, HIDDEN);
  convw_k<<<(HIDDEN * EMBD + 255) / 256, 256, 0, stream>>>(W3, Wt3, HIDDEN, EMBD);
  prescale_k<<<(NODES * FIN / 4 + 255) / 256, 256, 0, stream>>>(x, dinv, F0);

  const int aggBlocks = (NODES * 64 + 255) / 256;  // 25000
  const int gemmRows = (NODES + 127) / 128;        // 782

  // L1: AX = dinv*(sum xs) [128 f16]; H1s = dinv*relu(AX@W1+b1) [256 f16]
  agg_h<2, false><<<aggBlocks, 256, 0, stream>>>(F0, F1, row_ptr, csr_src, dinv, nullptr);
  gemm_h<FIN, true, true, true><<<dim3(gemmRows, 2), 256, 0, stream>>>(F1, Wt1, b1, dinv, F0, NODES, HIDDEN);
  // L2: AH1 = dinv*(sum H1s) [256 f16]; H2s = dinv*relu(AH1@W2+b2) [256 f16]
  agg_h<4, false><<<aggBlocks, 256, 0, stream>>>(F0, F1, row_ptr, csr_src, dinv, nullptr);
  gemm_h<HIDDEN, true, true, true><<<dim3(gemmRows, 2), 256, 0, stream>>>(F1, Wt2, b2, dinv, F0, NODES, HIDDEN);
  // L3: G3s = H2s@W3 [128 f16] (prescale carried through); H3 = dinv*(sum G3s)+b3 [128 f32]
  gemm_h<HIDDEN, false, false, false><<<dim3(gemmRows, 1), 256, 0, stream>>>(F0, Wt3, nullptr, nullptr, F1, NODES, EMBD);
  agg_h<2, true><<<aggBlocks, 256, 0, stream>>>(F1, R0, row_ptr, csr_src, dinv, b3);

  // pooling + MLP head (fp32)
  pool_k<<<GRAPHS, 128, 0, stream>>>(R0, batch, pooled);
  gemm_k<EMBD, true, true><<<dim3((GRAPHS + 127) / 128, 2), 256, 0, stream>>>(pooled, Wc1, bc1, z1, GRAPHS, HIDDEN);
  gemm_k<HIDDEN, true, true><<<dim3((GRAPHS + 127) / 128, 1), 256, 0, stream>>>(z1, Wc2, bc2, z2, GRAPHS, EMBD);
  head_k<<<GRAPHS / 4, 256, 0, stream>>>(z2, Wc3, bc3, out);
}

// Round 5
// 715.881 us; speedup vs baseline: 1.4124x; 1.4124x over previous
//
#include <hip/hip_runtime.h>
#include <cstdint>
#include <cstddef>

#define NODES  100000
#define EDGES  3200000
#define FIN    128
#define HIDDEN 256
#define EMBD   128
#define GRAPHS 2048

// bucket bin-sort geometry
#define NB   256            // buckets
#define NPB  391            // nodes per bucket (ceil(100000/256))
#define CAP  16384          // staging capacity per bucket (exp ~12.5K, 30+ sigma slack)
#define TILE 4096           // edges per phase-A block

typedef _Float16 f16;
typedef f16 f16x2 __attribute__((ext_vector_type(2)));
typedef f16 f16x4 __attribute__((ext_vector_type(4)));
typedef f16 f16x8 __attribute__((ext_vector_type(8)));
typedef float f32x4 __attribute__((ext_vector_type(4)));
typedef unsigned int u32;

// ---------------- Phase A: bin edges by dst-bucket into staging ----------------
// staging word = (src << 9) | (dst - bucket*NPB);  src<2^17, local<391<2^9
__global__ __launch_bounds__(256) void binA_k(const int* __restrict__ src,
                                              const int* __restrict__ dst,
                                              u32* __restrict__ staging,
                                              int* __restrict__ gcur) {
  __shared__ u32 buf[TILE];
  __shared__ int bcnt[NB], bsh[NB], bstart[NB], bcur[NB], gbase[NB];
  const int tid = threadIdx.x;
  const int tb = blockIdx.x * TILE;

  bcnt[tid] = 0;
  __syncthreads();

  // pass 1: count per bucket
#pragma unroll
  for (int j = 0; j < TILE / 256; ++j) {
    int i = tb + j * 256 + tid;
    if (i < EDGES) atomicAdd(&bcnt[dst[i] / NPB], 1);
  }
  __syncthreads();

  // inclusive scan of counts (Hillis-Steele over 256)
  bsh[tid] = bcnt[tid];
  __syncthreads();
  for (int off = 1; off < NB; off <<= 1) {
    int t = (tid >= off) ? bsh[tid - off] : 0;
    __syncthreads();
    bsh[tid] += t;
    __syncthreads();
  }
  bstart[tid] = bsh[tid] - bcnt[tid];
  bcur[tid] = bsh[tid] - bcnt[tid];
  __syncthreads();

  // pass 2: scatter packed words into bucket-ordered LDS
#pragma unroll
  for (int j = 0; j < TILE / 256; ++j) {
    int i = tb + j * 256 + tid;
    if (i < EDGES) {
      int d = dst[i];
      int b = d / NPB;
      u32 w = ((u32)src[i] << 9) | (u32)(d - b * NPB);
      buf[atomicAdd(&bcur[b], 1)] = w;
    }
  }
  // reserve global ranges (256 atomics per tile)
  gbase[tid] = atomicAdd(&gcur[tid], bcnt[tid]);
  __syncthreads();

  // copy-out: thread t owns bucket t; consecutive stores -> dense lines
  {
    int c = bcnt[tid], st = bstart[tid];
    u32* outp = staging + (size_t)tid * CAP + gbase[tid];
    for (int k = 0; k < c; ++k) outp[k] = buf[st + k];
  }
}

// ---------------- bucket-base exclusive scan (1 block) ----------------
__global__ void bscan_k(const int* __restrict__ gcur, int* __restrict__ bbase) {
  __shared__ int sh[NB];
  int tid = threadIdx.x;
  int v = gcur[tid];
  sh[tid] = v;
  __syncthreads();
  for (int off = 1; off < NB; off <<= 1) {
    int t = (tid >= off) ? sh[tid - off] : 0;
    __syncthreads();
    sh[tid] += t;
    __syncthreads();
  }
  bbase[tid] = sh[tid] - v;  // exclusive
}

// ---------------- Phase B: per-bucket CSR finalize (row_ptr, dinv, csr_src) ----------------
__global__ __launch_bounds__(512) void binB_k(const u32* __restrict__ staging,
                                              const int* __restrict__ gcur,
                                              const int* __restrict__ bbase,
                                              int* __restrict__ row_ptr,
                                              float* __restrict__ dinv,
                                              int* __restrict__ csr_src) {
  __shared__ int ncnt[512];
  __shared__ int ncur[512];
  const int b = blockIdx.x;
  const int tid = threadIdx.x;
  const int m = gcur[b];
  const int base = bbase[b];
  const int nb0 = b * NPB;
  const int nn = min(NPB, NODES - nb0);
  const u32* sb = staging + (size_t)b * CAP;

  ncnt[tid] = 0;
  __syncthreads();

  // count per local node
  for (int k = tid; k < m; k += 512) atomicAdd(&ncnt[sb[k] & 511], 1);
  __syncthreads();

  int v = ncnt[tid];
  // in-place inclusive scan over 512
  for (int off = 1; off < 512; off <<= 1) {
    int t = (tid >= off) ? ncnt[tid - off] : 0;
    __syncthreads();
    ncnt[tid] += t;
    __syncthreads();
  }
  int incl = ncnt[tid];
  if (tid < nn) {
    row_ptr[nb0 + tid + 1] = base + incl;
    dinv[nb0 + tid] = rsqrtf((float)(v + 1));
    ncur[tid] = base + incl - v;  // global cursor start (exclusive)
  }
  if (b == 0 && tid == 0) row_ptr[0] = 0;
  __syncthreads();

  // scatter src into block-owned contiguous csr region (dense writes)
  for (int k = tid; k < m; k += 512) {
    u32 w = sb[k];
    int pos = atomicAdd(&ncur[w & 511], 1);
    csr_src[pos] = (int)(w >> 9);
  }
}

// ---------------- prescale: xs[i] = f16(dinv[i] * x[i]) ----------------
__global__ void prescale_k(const float* __restrict__ x, const float* __restrict__ dinv,
                           f16* __restrict__ xs) {
  int idx = blockIdx.x * blockDim.x + threadIdx.x;  // over NODES*FIN/4
  if (idx >= NODES * FIN / 4) return;
  int row = idx >> 5;  // FIN/4 = 32 float4 per row
  float4 v = *(const float4*)(x + (size_t)idx * 4);
  float d = dinv[row];
  f16x4 o = {(f16)(d * v.x), (f16)(d * v.y), (f16)(d * v.z), (f16)(d * v.w)};
  *(f16x4*)(xs + (size_t)idx * 4) = o;
}

// ---------------- weight convert+transpose: Wt[m][k] = f16(W[k][m]) ----------------
__global__ void convw_k(const float* __restrict__ W, f16* __restrict__ Wt, int K, int M) {
  int i = blockIdx.x * blockDim.x + threadIdx.x;
  if (i >= K * M) return;
  int k = i / M, m = i - k * M;
  Wt[(size_t)m * K + k] = (f16)W[i];
}

// ---------------- aggregation (f16 in, fp32 accum), 8-deep MLP unroll ----------------
// in is dinv-prescaled: out[i] = dinv[i] * (sum_{s in N(i)} in[s] + in[i]) (+bias, FINAL->fp32)
template <int V, bool FINAL>
__global__ __launch_bounds__(256) void agg_h(const f16* __restrict__ in, void* __restrict__ outv,
                      const int* __restrict__ row_ptr, const int* __restrict__ csr_src,
                      const float* __restrict__ dinv, const float* __restrict__ bias) {
  constexpr int D = V * 64;
  constexpr int U = 8;  // gathers kept in flight (U=16 regressed: occupancy 78->54%)
  int node = (blockIdx.x * blockDim.x + threadIdx.x) >> 6;
  int lane = threadIdx.x & 63;
  if (node >= NODES) return;
  const int c0 = lane * V;
  const f16* __restrict__ inc = in + c0;

  float acc[V];
#pragma unroll
  for (int v = 0; v < V; ++v) acc[v] = 0.f;

  int beg = row_ptr[node], end = row_ptr[node + 1];
  int k = beg;
  for (; k + U <= end; k += U) {
    int s[U];
#pragma unroll
    for (int u = 0; u < U; ++u) s[u] = csr_src[k + u];
    if (V == 4) {
      f16x4 hv[U];
#pragma unroll
      for (int u = 0; u < U; ++u) hv[u] = *(const f16x4*)(inc + (size_t)s[u] * D);
#pragma unroll
      for (int u = 0; u < U; ++u) {
        acc[0] += (float)hv[u][0]; acc[1] += (float)hv[u][1];
        acc[2] += (float)hv[u][2]; acc[3] += (float)hv[u][3];
      }
    } else {
      f16x2 hv[U];
#pragma unroll
      for (int u = 0; u < U; ++u) hv[u] = *(const f16x2*)(inc + (size_t)s[u] * D);
#pragma unroll
      for (int u = 0; u < U; ++u) {
        acc[0] += (float)hv[u][0]; acc[1] += (float)hv[u][1];
      }
    }
  }
  // tail
  for (; k < end; ++k) {
    int s = csr_src[k];
    if (V == 4) {
      f16x4 hv = *(const f16x4*)(inc + (size_t)s * D);
      acc[0] += (float)hv[0]; acc[1] += (float)hv[1];
      acc[2] += (float)hv[2]; acc[3] += (float)hv[3];
    } else {
      f16x2 hv = *(const f16x2*)(inc + (size_t)s * D);
      acc[0] += (float)hv[0]; acc[1] += (float)hv[1];
    }
  }
  // self-loop term
  if (V == 4) {
    f16x4 hv = *(const f16x4*)(inc + (size_t)node * D);
    acc[0] += (float)hv[0]; acc[1] += (float)hv[1];
    acc[2] += (float)hv[2]; acc[3] += (float)hv[3];
  } else {
    f16x2 hv = *(const f16x2*)(inc + (size_t)node * D);
    acc[0] += (float)hv[0]; acc[1] += (float)hv[1];
  }

  float di = dinv[node];
  if (FINAL) {
    float* out = (float*)outv;
    if (V == 4) {
      float4 o = {di * acc[0] + bias[c0], di * acc[1] + bias[c0 + 1],
                  di * acc[2] + bias[c0 + 2], di * acc[3] + bias[c0 + 3]};
      *(float4*)(out + (size_t)node * D + c0) = o;
    } else {
      float2 o = {di * acc[0] + bias[c0], di * acc[1] + bias[c0 + 1]};
      *(float2*)(out + (size_t)node * D + c0) = o;
    }
  } else {
    f16* out = (f16*)outv;
    if (V == 4) {
      f16x4 o = {(f16)(di * acc[0]), (f16)(di * acc[1]),
                 (f16)(di * acc[2]), (f16)(di * acc[3])};
      *(f16x4*)(out + (size_t)node * D + c0) = o;
    } else {
      f16x2 o = {(f16)(di * acc[0]), (f16)(di * acc[1])};
      *(f16x2*)(out + (size_t)node * D + c0) = o;
    }
  }
}

// ---------------- f16 MFMA GEMM: C[N,M] = epi(A[N,K] @ W[K,M]) ----------------
template <int K, bool RELU, bool BIAS, bool DSCALE>
__global__ __launch_bounds__(256) void gemm_h(const f16* __restrict__ A,
                                              const f16* __restrict__ Wt,
                                              const float* __restrict__ bias,
                                              const float* __restrict__ dinv,
                                              f16* __restrict__ C, int N, int M) {
  __shared__ f16 As[128][40];  // [row][k], pad to 40 halves (80B) for bank spread
  __shared__ f16 Bs[128][40];  // [col][k]

  const int tid = threadIdx.x;
  const int rowbase = blockIdx.x * 128;
  const int colbase = blockIdx.y * 128;
  const int l = tid & 63;
  const int wr = ((tid >> 6) >> 1) * 64;  // wave row offset 0/64
  const int wc = ((tid >> 6) & 1) * 64;   // wave col offset 0/64
  const int lr = tid >> 1;                // 0..127: tile row (A) / tile col (B)
  const int lc = (tid & 1) * 16;          // half-offset within BK=32

  f32x4 acc[4][4];
#pragma unroll
  for (int i = 0; i < 4; ++i)
#pragma unroll
    for (int j = 0; j < 4; ++j) acc[i][j] = (f32x4){0.f, 0.f, 0.f, 0.f};

  const int arow = min(rowbase + lr, N - 1);  // clamp: OOB rows read row N-1, never stored
  const f16* aptr = A + (size_t)arow * K + lc;
  const f16* bptr = Wt + (size_t)(colbase + lr) * K + lc;

  for (int kb = 0; kb < K; kb += 32) {
    *(f16x8*)&As[lr][lc]     = *(const f16x8*)(aptr + kb);
    *(f16x8*)&As[lr][lc + 8] = *(const f16x8*)(aptr + kb + 8);
    *(f16x8*)&Bs[lr][lc]     = *(const f16x8*)(bptr + kb);
    *(f16x8*)&Bs[lr][lc + 8] = *(const f16x8*)(bptr + kb + 8);
    __syncthreads();

    f16x8 a[4], b[4];
#pragma unroll
    for (int f = 0; f < 4; ++f) {
      a[f] = *(const f16x8*)&As[wr + f * 16 + (l & 15)][(l >> 4) * 8];
      b[f] = *(const f16x8*)&Bs[wc + f * 16 + (l & 15)][(l >> 4) * 8];
    }
#pragma unroll
    for (int fm = 0; fm < 4; ++fm)
#pragma unroll
      for (int fn = 0; fn < 4; ++fn)
        acc[fm][fn] = __builtin_amdgcn_mfma_f32_16x16x32_f16(a[fm], b[fn], acc[fm][fn], 0, 0, 0);
    __syncthreads();
  }

  float bv[4];
#pragma unroll
  for (int fn = 0; fn < 4; ++fn)
    bv[fn] = BIAS ? bias[colbase + wc + fn * 16 + (l & 15)] : 0.f;

#pragma unroll
  for (int fm = 0; fm < 4; ++fm) {
#pragma unroll
    for (int r = 0; r < 4; ++r) {
      int row = rowbase + wr + fm * 16 + (l >> 4) * 4 + r;
      if (row >= N) continue;
      float dv = DSCALE ? dinv[row] : 1.f;
#pragma unroll
      for (int fn = 0; fn < 4; ++fn) {
        int col = colbase + wc + fn * 16 + (l & 15);
        float v = acc[fm][fn][r] + bv[fn];
        if (RELU) v = fmaxf(v, 0.f);
        C[(size_t)row * M + col] = (f16)(v * dv);
      }
    }
  }
}

// ---------------- fp32 GEMM for the tiny head (N=2048) ----------------
template <int K, bool RELU, bool HAS_BIAS>
__global__ __launch_bounds__(256) void gemm_k(const float* __restrict__ A,
                                              const float* __restrict__ W,
                                              const float* __restrict__ bias,
                                              float* __restrict__ C, int N, int M) {
  constexpr int KB = 16;
  __shared__ float As[KB][128];
  __shared__ float Ws[KB][128];

  const int tid = threadIdx.x;
  const int rowbase = blockIdx.x * 128;
  const int colbase = blockIdx.y * 128;
  const int tr = tid >> 4;
  const int tc = tid & 15;
  const int ar = tid >> 1;
  const int ac4_0 = (tid & 1) * 2;
  const int wk = tid >> 4;
  const int wc4_0 = (tid & 15) * 2;

  float acc[8][8];
#pragma unroll
  for (int i = 0; i < 8; ++i)
#pragma unroll
    for (int j = 0; j < 8; ++j) acc[i][j] = 0.f;

  for (int kb = 0; kb < K; kb += KB) {
#pragma unroll
    for (int q = 0; q < 2; ++q) {
      int c4 = ac4_0 + q;
      int grow = rowbase + ar;
      float4 v = make_float4(0.f, 0.f, 0.f, 0.f);
      if (grow < N) v = *(const float4*)(A + (size_t)grow * K + kb + c4 * 4);
      As[c4 * 4 + 0][ar] = v.x;
      As[c4 * 4 + 1][ar] = v.y;
      As[c4 * 4 + 2][ar] = v.z;
      As[c4 * 4 + 3][ar] = v.w;
    }
#pragma unroll
    for (int q = 0; q < 2; ++q) {
      int c4 = wc4_0 + q;
      float4 v = *(const float4*)(W + (size_t)(kb + wk) * M + colbase + c4 * 4);
      *(float4*)&Ws[wk][c4 * 4] = v;
    }
    __syncthreads();

#pragma unroll
    for (int kk = 0; kk < KB; ++kk) {
      float4 a0 = *(const float4*)&As[kk][tr * 4];
      float4 a1 = *(const float4*)&As[kk][tr * 4 + 64];
      float4 w0 = *(const float4*)&Ws[kk][tc * 4];
      float4 w1 = *(const float4*)&Ws[kk][tc * 4 + 64];
      float a[8] = {a0.x, a0.y, a0.z, a0.w, a1.x, a1.y, a1.z, a1.w};
      float w[8] = {w0.x, w0.y, w0.z, w0.w, w1.x, w1.y, w1.z, w1.w};
#pragma unroll
      for (int i = 0; i < 8; ++i)
#pragma unroll
        for (int j = 0; j < 8; ++j) acc[i][j] = fmaf(a[i], w[j], acc[i][j]);
    }
    __syncthreads();
  }

#pragma unroll
  for (int i = 0; i < 8; ++i) {
    int r = rowbase + ((i < 4) ? (tr * 4 + i) : (64 + tr * 4 + (i - 4)));
    if (r >= N) continue;
#pragma unroll
    for (int jh = 0; jh < 2; ++jh) {
      int c = colbase + tc * 4 + jh * 64;
      float4 o;
      o.x = acc[i][jh * 4 + 0];
      o.y = acc[i][jh * 4 + 1];
      o.z = acc[i][jh * 4 + 2];
      o.w = acc[i][jh * 4 + 3];
      if (HAS_BIAS) {
        o.x += bias[c]; o.y += bias[c + 1]; o.z += bias[c + 2]; o.w += bias[c + 3];
      }
      if (RELU) {
        o.x = fmaxf(o.x, 0.f); o.y = fmaxf(o.y, 0.f);
        o.z = fmaxf(o.z, 0.f); o.w = fmaxf(o.w, 0.f);
      }
      *(float4*)(C + (size_t)r * M + c) = o;
    }
  }
}

// ---------------- mean pooling per graph (batch sorted) ----------------
__global__ void pool_k(const float* __restrict__ h, const int* __restrict__ batch,
                       float* __restrict__ pooled) {
  int g = blockIdx.x;
  int j = threadIdx.x;  // 128 threads = EMBD
  int lo = 0, hi = NODES;
  while (lo < hi) { int mid = (lo + hi) >> 1; if (batch[mid] < g) lo = mid + 1; else hi = mid; }
  int start = lo;
  int lo2 = start, hi2 = NODES;
  while (lo2 < hi2) { int mid = (lo2 + hi2) >> 1; if (batch[mid] < g + 1) lo2 = mid + 1; else hi2 = mid; }
  int end = lo2;
  float s = 0.f;
  for (int r = start; r < end; ++r) s += h[(size_t)r * EMBD + j];
  float c = (float)(end - start);
  pooled[g * EMBD + j] = s / fmaxf(c, 1.f);
}

// ---------------- head: logits = z2 @ Wc3[128,2] + bc3 ----------------
__global__ void head_k(const float* __restrict__ z2, const float* __restrict__ Wc3,
                       const float* __restrict__ bc3, float* __restrict__ out) {
  int wv = (blockIdx.x * blockDim.x + threadIdx.x) >> 6;
  int lane = threadIdx.x & 63;
  if (wv >= GRAPHS) return;
  float2 z = *(const float2*)(z2 + (size_t)wv * 128 + lane * 2);
  int j0 = lane * 2;
  float a0 = z.x * Wc3[j0 * 2 + 0] + z.y * Wc3[(j0 + 1) * 2 + 0];
  float a1 = z.x * Wc3[j0 * 2 + 1] + z.y * Wc3[(j0 + 1) * 2 + 1];
  for (int off = 32; off; off >>= 1) {
    a0 += __shfl_down(a0, off);
    a1 += __shfl_down(a1, off);
  }
  if (lane == 0) {
    out[wv * 2 + 0] = a0 + bc3[0];
    out[wv * 2 + 1] = a1 + bc3[1];
  }
}

extern "C" void kernel_launch(void* const* d_in, const int* in_sizes, int n_in,
                              void* d_out, int out_size, void* d_ws, size_t ws_size,
                              hipStream_t stream) {
  const float* x    = (const float*)d_in[0];
  const int*   ei   = (const int*)d_in[1];
  const int*   batch= (const int*)d_in[2];
  const float* W1 = (const float*)d_in[3];  const float* b1 = (const float*)d_in[4];
  const float* W2 = (const float*)d_in[5];  const float* b2 = (const float*)d_in[6];
  const float* W3 = (const float*)d_in[7];  const float* b3 = (const float*)d_in[8];
  const float* Wc1= (const float*)d_in[9];  const float* bc1= (const float*)d_in[10];
  const float* Wc2= (const float*)d_in[11]; const float* bc2= (const float*)d_in[12];
  const float* Wc3= (const float*)d_in[13]; const float* bc3= (const float*)d_in[14];
  float* out = (float*)d_out;

  char* ws = (char*)d_ws;
  size_t off = 0;
  auto alloc = [&](size_t bytes) -> void* {
    void* p = ws + off;
    off = (off + bytes + 255) & ~(size_t)255;
    return p;
  };
  f16*   F0      = (f16*)alloc((size_t)NODES * 256 * 2);
  f16*   F1      = (f16*)alloc((size_t)NODES * 256 * 2);
  float* R0      = (float*)alloc((size_t)NODES * 128 * 4);
  int*   csr_src = (int*)alloc((size_t)EDGES * 4);
  u32*   staging = (u32*)alloc((size_t)NB * CAP * 4);
  int*   row_ptr = (int*)alloc((size_t)(NODES + 1) * 4);
  float* dinv    = (float*)alloc((size_t)NODES * 4);
  int*   gcur    = (int*)alloc(NB * 4);
  int*   bbase   = (int*)alloc(NB * 4);
  f16*   Wt1     = (f16*)alloc((size_t)FIN * HIDDEN * 2);
  f16*   Wt2     = (f16*)alloc((size_t)HIDDEN * HIDDEN * 2);
  f16*   Wt3     = (f16*)alloc((size_t)HIDDEN * EMBD * 2);
  // fp32 overlays in F0 (dead after GEMM3 consumed it -> reused post-agg3)
  float* pooled = (float*)F0;
  float* z1     = pooled + (size_t)GRAPHS * EMBD;
  float* z2     = z1 + (size_t)GRAPHS * HIDDEN;

  const int* srcA = ei;
  const int* dstA = ei + EDGES;

  // ---- CSR build: two-phase LDS bin-sort (no per-edge global atomics) ----
  hipMemsetAsync(gcur, 0, NB * 4, stream);
  binA_k<<<(EDGES + TILE - 1) / TILE, 256, 0, stream>>>(srcA, dstA, staging, gcur);
  bscan_k<<<1, NB, 0, stream>>>(gcur, bbase);
  binB_k<<<NB, 512, 0, stream>>>(staging, gcur, bbase, row_ptr, dinv, csr_src);

  convw_k<<<(FIN * HIDDEN + 255) / 256, 256, 0, stream>>>(W1, Wt1, FIN, HIDDEN);
  convw_k<<<(HIDDEN * HIDDEN + 255) / 256, 256, 0, stream>>>(W2, Wt2, HIDDEN, HIDDEN);
  convw_k<<<(HIDDEN * EMBD + 255) / 256, 256, 0, stream>>>(W3, Wt3, HIDDEN, EMBD);
  prescale_k<<<(NODES * FIN / 4 + 255) / 256, 256, 0, stream>>>(x, dinv, F0);

  const int aggBlocks = (NODES * 64 + 255) / 256;  // 25000
  const int gemmRows = (NODES + 127) / 128;        // 782

  // L1: AX = dinv*(sum xs) [128 f16]; H1s = dinv*relu(AX@W1+b1) [256 f16]
  agg_h<2, false><<<aggBlocks, 256, 0, stream>>>(F0, F1, row_ptr, csr_src, dinv, nullptr);
  gemm_h<FIN, true, true, true><<<dim3(gemmRows, 2), 256, 0, stream>>>(F1, Wt1, b1, dinv, F0, NODES, HIDDEN);
  // L2: AH1 = dinv*(sum H1s) [256 f16]; H2s = dinv*relu(AH1@W2+b2) [256 f16]
  agg_h<4, false><<<aggBlocks, 256, 0, stream>>>(F0, F1, row_ptr, csr_src, dinv, nullptr);
  gemm_h<HIDDEN, true, true, true><<<dim3(gemmRows, 2), 256, 0, stream>>>(F1, Wt2, b2, dinv, F0, NODES, HIDDEN);
  // L3: G3s = H2s@W3 [128 f16] (prescale carried through); H3 = dinv*(sum G3s)+b3 [128 f32]
  gemm_h<HIDDEN, false, false, false><<<dim3(gemmRows, 1), 256, 0, stream>>>(F0, Wt3, nullptr, nullptr, F1, NODES, EMBD);
  agg_h<2, true><<<aggBlocks, 256, 0, stream>>>(F1, R0, row_ptr, csr_src, dinv, b3);

  // pooling + MLP head (fp32)
  pool_k<<<GRAPHS, 128, 0, stream>>>(R0, batch, pooled);
  gemm_k<EMBD, true, true><<<dim3((GRAPHS + 127) / 128, 2), 256, 0, stream>>>(pooled, Wc1, bc1, z1, GRAPHS, HIDDEN);
  gemm_k<HIDDEN, true, true><<<dim3((GRAPHS + 127) / 128, 1), 256, 0, stream>>>(z1, Wc2, bc2, z2, GRAPHS, EMBD);
  head_k<<<GRAPHS / 4, 256, 0, stream>>>(z2, Wc3, bc3, out);
}

// Round 6
// 707.910 us; speedup vs baseline: 1.4283x; 1.0113x over previous
//
#include <hip/hip_runtime.h>
#include <cstdint>
#include <cstddef>

#define NODES  100000
#define EDGES  3200000
#define FIN    128
#define HIDDEN 256
#define EMBD   128
#define GRAPHS 2048

// bucket bin-sort geometry
#define NB   256            // buckets
#define NPB  391            // nodes per bucket (ceil(100000/256))
#define CAP  16384          // staging capacity per bucket (exp ~12.5K, 30+ sigma slack)
#define TILE 4096           // edges per phase-A block

typedef _Float16 f16;
typedef f16 f16x2 __attribute__((ext_vector_type(2)));
typedef f16 f16x4 __attribute__((ext_vector_type(4)));
typedef f16 f16x8 __attribute__((ext_vector_type(8)));
typedef float f32x4 __attribute__((ext_vector_type(4)));
typedef unsigned int u32;

// ---------------- Phase A: bin edges by dst-bucket into staging ----------------
// staging word = (src << 9) | (dst - bucket*NPB);  src<2^17, local<391<2^9
__global__ __launch_bounds__(256) void binA_k(const int* __restrict__ src,
                                              const int* __restrict__ dst,
                                              u32* __restrict__ staging,
                                              int* __restrict__ gcur) {
  __shared__ u32 buf[TILE];
  __shared__ int bcnt[NB], bsh[NB], bstart[NB], bcur[NB], gbase[NB];
  const int tid = threadIdx.x;
  const int tb = blockIdx.x * TILE;

  bcnt[tid] = 0;
  __syncthreads();

  // pass 1: count per bucket
#pragma unroll
  for (int j = 0; j < TILE / 256; ++j) {
    int i = tb + j * 256 + tid;
    if (i < EDGES) atomicAdd(&bcnt[dst[i] / NPB], 1);
  }
  __syncthreads();

  // inclusive scan of counts (Hillis-Steele over 256)
  bsh[tid] = bcnt[tid];
  __syncthreads();
  for (int off = 1; off < NB; off <<= 1) {
    int t = (tid >= off) ? bsh[tid - off] : 0;
    __syncthreads();
    bsh[tid] += t;
    __syncthreads();
  }
  bstart[tid] = bsh[tid] - bcnt[tid];
  bcur[tid] = bsh[tid] - bcnt[tid];
  __syncthreads();

  // pass 2: scatter packed words into bucket-ordered LDS
#pragma unroll
  for (int j = 0; j < TILE / 256; ++j) {
    int i = tb + j * 256 + tid;
    if (i < EDGES) {
      int d = dst[i];
      int b = d / NPB;
      u32 w = ((u32)src[i] << 9) | (u32)(d - b * NPB);
      buf[atomicAdd(&bcur[b], 1)] = w;
    }
  }
  // reserve global ranges (256 atomics per tile)
  gbase[tid] = atomicAdd(&gcur[tid], bcnt[tid]);
  __syncthreads();

  // copy-out: thread t owns bucket t; consecutive stores -> dense lines
  {
    int c = bcnt[tid], st = bstart[tid];
    u32* outp = staging + (size_t)tid * CAP + gbase[tid];
    for (int k = 0; k < c; ++k) outp[k] = buf[st + k];
  }
}

// ---------------- bucket-base exclusive scan (1 block) ----------------
__global__ void bscan_k(const int* __restrict__ gcur, int* __restrict__ bbase) {
  __shared__ int sh[NB];
  int tid = threadIdx.x;
  int v = gcur[tid];
  sh[tid] = v;
  __syncthreads();
  for (int off = 1; off < NB; off <<= 1) {
    int t = (tid >= off) ? sh[tid - off] : 0;
    __syncthreads();
    sh[tid] += t;
    __syncthreads();
  }
  bbase[tid] = sh[tid] - v;  // exclusive
}

// ---------------- Phase B: per-bucket CSR finalize (row_ptr, dinv, csr_src) ----------------
__global__ __launch_bounds__(512) void binB_k(const u32* __restrict__ staging,
                                              const int* __restrict__ gcur,
                                              const int* __restrict__ bbase,
                                              int* __restrict__ row_ptr,
                                              float* __restrict__ dinv,
                                              int* __restrict__ csr_src) {
  __shared__ int ncnt[512];
  __shared__ int ncur[512];
  const int b = blockIdx.x;
  const int tid = threadIdx.x;
  const int m = gcur[b];
  const int base = bbase[b];
  const int nb0 = b * NPB;
  const int nn = min(NPB, NODES - nb0);
  const u32* sb = staging + (size_t)b * CAP;

  ncnt[tid] = 0;
  __syncthreads();

  // count per local node
  for (int k = tid; k < m; k += 512) atomicAdd(&ncnt[sb[k] & 511], 1);
  __syncthreads();

  int v = ncnt[tid];
  // in-place inclusive scan over 512
  for (int off = 1; off < 512; off <<= 1) {
    int t = (tid >= off) ? ncnt[tid - off] : 0;
    __syncthreads();
    ncnt[tid] += t;
    __syncthreads();
  }
  int incl = ncnt[tid];
  if (tid < nn) {
    row_ptr[nb0 + tid + 1] = base + incl;
    dinv[nb0 + tid] = rsqrtf((float)(v + 1));
    ncur[tid] = base + incl - v;  // global cursor start (exclusive)
  }
  if (b == 0 && tid == 0) row_ptr[0] = 0;
  __syncthreads();

  // scatter src into block-owned contiguous csr region (dense writes)
  for (int k = tid; k < m; k += 512) {
    u32 w = sb[k];
    int pos = atomicAdd(&ncur[w & 511], 1);
    csr_src[pos] = (int)(w >> 9);
  }
}

// ---------------- prescale: xs[i] = f16(dinv[i] * x[i]) ----------------
__global__ void prescale_k(const float* __restrict__ x, const float* __restrict__ dinv,
                           f16* __restrict__ xs) {
  int idx = blockIdx.x * blockDim.x + threadIdx.x;  // over NODES*FIN/4
  if (idx >= NODES * FIN / 4) return;
  int row = idx >> 5;  // FIN/4 = 32 float4 per row
  float4 v = *(const float4*)(x + (size_t)idx * 4);
  float d = dinv[row];
  f16x4 o = {(f16)(d * v.x), (f16)(d * v.y), (f16)(d * v.z), (f16)(d * v.w)};
  *(f16x4*)(xs + (size_t)idx * 4) = o;
}

// ---------------- weight convert+transpose: Wt[m][k] = f16(W[k][m]) ----------------
__global__ void convw_k(const float* __restrict__ W, f16* __restrict__ Wt, int K, int M) {
  int i = blockIdx.x * blockDim.x + threadIdx.x;
  if (i >= K * M) return;
  int k = i / M, m = i - k * M;
  Wt[(size_t)m * K + k] = (f16)W[i];
}

// ---------------- aggregation (f16 in, fp32 accum) ----------------
// 2 nodes per wave (32 lanes x V f16 each): one load instruction carries two
// independent edge-gathers -> 2x memory-level parallelism at same occupancy.
// in is dinv-prescaled: out[i] = dinv[i] * (sum_{s in N(i)} in[s] + in[i]) (+bias, FINAL->fp32)
template <int V, bool FINAL>
__global__ __launch_bounds__(256) void agg_h(const f16* __restrict__ in, void* __restrict__ outv,
                      const int* __restrict__ row_ptr, const int* __restrict__ csr_src,
                      const float* __restrict__ dinv, const float* __restrict__ bias) {
  constexpr int D = V * 32;   // row width in f16
  constexpr int U = 8;        // gathers in flight per node stream (16/wave)
  const int wid = (blockIdx.x * blockDim.x + threadIdx.x) >> 6;
  const int half = (threadIdx.x >> 5) & 1;
  const int lane = threadIdx.x & 31;
  const int node = wid * 2 + half;
  if (node >= NODES) return;
  const int c0 = lane * V;
  const f16* __restrict__ inc = in + c0;

  float acc[V];
#pragma unroll
  for (int v = 0; v < V; ++v) acc[v] = 0.f;

  const int beg = row_ptr[node], end = row_ptr[node + 1];
  int k = beg;
  if constexpr (V == 8) {
    for (; k + U <= end; k += U) {
      int s[U];
#pragma unroll
      for (int u = 0; u < U; ++u) s[u] = csr_src[k + u];
      f16x8 hv[U];
#pragma unroll
      for (int u = 0; u < U; ++u) hv[u] = *(const f16x8*)(inc + (size_t)s[u] * D);
#pragma unroll
      for (int u = 0; u < U; ++u)
#pragma unroll
        for (int v = 0; v < V; ++v) acc[v] += (float)hv[u][v];
    }
    for (; k < end; ++k) {
      f16x8 hv = *(const f16x8*)(inc + (size_t)csr_src[k] * D);
#pragma unroll
      for (int v = 0; v < V; ++v) acc[v] += (float)hv[v];
    }
    f16x8 hv = *(const f16x8*)(inc + (size_t)node * D);  // self loop
#pragma unroll
    for (int v = 0; v < V; ++v) acc[v] += (float)hv[v];
  } else {
    for (; k + U <= end; k += U) {
      int s[U];
#pragma unroll
      for (int u = 0; u < U; ++u) s[u] = csr_src[k + u];
      f16x4 hv[U];
#pragma unroll
      for (int u = 0; u < U; ++u) hv[u] = *(const f16x4*)(inc + (size_t)s[u] * D);
#pragma unroll
      for (int u = 0; u < U; ++u)
#pragma unroll
        for (int v = 0; v < V; ++v) acc[v] += (float)hv[u][v];
    }
    for (; k < end; ++k) {
      f16x4 hv = *(const f16x4*)(inc + (size_t)csr_src[k] * D);
#pragma unroll
      for (int v = 0; v < V; ++v) acc[v] += (float)hv[v];
    }
    f16x4 hv = *(const f16x4*)(inc + (size_t)node * D);  // self loop
#pragma unroll
    for (int v = 0; v < V; ++v) acc[v] += (float)hv[v];
  }

  const float di = dinv[node];
  if constexpr (FINAL) {  // V==4 path, fp32 out + bias
    float* out = (float*)outv;
    float4 o = {di * acc[0] + bias[c0], di * acc[1] + bias[c0 + 1],
                di * acc[2] + bias[c0 + 2], di * acc[3] + bias[c0 + 3]};
    *(float4*)(out + (size_t)node * D + c0) = o;
  } else {
    f16* out = (f16*)outv;
    if constexpr (V == 8) {
      f16x8 o;
#pragma unroll
      for (int v = 0; v < V; ++v) o[v] = (f16)(di * acc[v]);
      *(f16x8*)(out + (size_t)node * D + c0) = o;
    } else {
      f16x4 o;
#pragma unroll
      for (int v = 0; v < V; ++v) o[v] = (f16)(di * acc[v]);
      *(f16x4*)(out + (size_t)node * D + c0) = o;
    }
  }
}

// ---------------- f16 MFMA GEMM: C[N,M] = epi(A[N,K] @ W[K,M]) ----------------
template <int K, bool RELU, bool BIAS, bool DSCALE>
__global__ __launch_bounds__(256) void gemm_h(const f16* __restrict__ A,
                                              const f16* __restrict__ Wt,
                                              const float* __restrict__ bias,
                                              const float* __restrict__ dinv,
                                              f16* __restrict__ C, int N, int M) {
  __shared__ f16 As[128][40];  // [row][k], pad to 40 halves (80B) for bank spread
  __shared__ f16 Bs[128][40];  // [col][k]

  const int tid = threadIdx.x;
  const int rowbase = blockIdx.x * 128;
  const int colbase = blockIdx.y * 128;
  const int l = tid & 63;
  const int wr = ((tid >> 6) >> 1) * 64;  // wave row offset 0/64
  const int wc = ((tid >> 6) & 1) * 64;   // wave col offset 0/64
  const int lr = tid >> 1;                // 0..127: tile row (A) / tile col (B)
  const int lc = (tid & 1) * 16;          // half-offset within BK=32

  f32x4 acc[4][4];
#pragma unroll
  for (int i = 0; i < 4; ++i)
#pragma unroll
    for (int j = 0; j < 4; ++j) acc[i][j] = (f32x4){0.f, 0.f, 0.f, 0.f};

  const int arow = min(rowbase + lr, N - 1);  // clamp: OOB rows read row N-1, never stored
  const f16* aptr = A + (size_t)arow * K + lc;
  const f16* bptr = Wt + (size_t)(colbase + lr) * K + lc;

  for (int kb = 0; kb < K; kb += 32) {
    *(f16x8*)&As[lr][lc]     = *(const f16x8*)(aptr + kb);
    *(f16x8*)&As[lr][lc + 8] = *(const f16x8*)(aptr + kb + 8);
    *(f16x8*)&Bs[lr][lc]     = *(const f16x8*)(bptr + kb);
    *(f16x8*)&Bs[lr][lc + 8] = *(const f16x8*)(bptr + kb + 8);
    __syncthreads();

    f16x8 a[4], b[4];
#pragma unroll
    for (int f = 0; f < 4; ++f) {
      a[f] = *(const f16x8*)&As[wr + f * 16 + (l & 15)][(l >> 4) * 8];
      b[f] = *(const f16x8*)&Bs[wc + f * 16 + (l & 15)][(l >> 4) * 8];
    }
#pragma unroll
    for (int fm = 0; fm < 4; ++fm)
#pragma unroll
      for (int fn = 0; fn < 4; ++fn)
        acc[fm][fn] = __builtin_amdgcn_mfma_f32_16x16x32_f16(a[fm], b[fn], acc[fm][fn], 0, 0, 0);
    __syncthreads();
  }

  float bv[4];
#pragma unroll
  for (int fn = 0; fn < 4; ++fn)
    bv[fn] = BIAS ? bias[colbase + wc + fn * 16 + (l & 15)] : 0.f;

#pragma unroll
  for (int fm = 0; fm < 4; ++fm) {
#pragma unroll
    for (int r = 0; r < 4; ++r) {
      int row = rowbase + wr + fm * 16 + (l >> 4) * 4 + r;
      if (row >= N) continue;
      float dv = DSCALE ? dinv[row] : 1.f;
#pragma unroll
      for (int fn = 0; fn < 4; ++fn) {
        int col = colbase + wc + fn * 16 + (l & 15);
        float v = acc[fm][fn][r] + bv[fn];
        if (RELU) v = fmaxf(v, 0.f);
        C[(size_t)row * M + col] = (f16)(v * dv);
      }
    }
  }
}

// ---------------- fp32 GEMM for the tiny head (N=2048) ----------------
template <int K, bool RELU, bool HAS_BIAS>
__global__ __launch_bounds__(256) void gemm_k(const float* __restrict__ A,
                                              const float* __restrict__ W,
                                              const float* __restrict__ bias,
                                              float* __restrict__ C, int N, int M) {
  constexpr int KB = 16;
  __shared__ float As[KB][128];
  __shared__ float Ws[KB][128];

  const int tid = threadIdx.x;
  const int rowbase = blockIdx.x * 128;
  const int colbase = blockIdx.y * 128;
  const int tr = tid >> 4;
  const int tc = tid & 15;
  const int ar = tid >> 1;
  const int ac4_0 = (tid & 1) * 2;
  const int wk = tid >> 4;
  const int wc4_0 = (tid & 15) * 2;

  float acc[8][8];
#pragma unroll
  for (int i = 0; i < 8; ++i)
#pragma unroll
    for (int j = 0; j < 8; ++j) acc[i][j] = 0.f;

  for (int kb = 0; kb < K; kb += KB) {
#pragma unroll
    for (int q = 0; q < 2; ++q) {
      int c4 = ac4_0 + q;
      int grow = rowbase + ar;
      float4 v = make_float4(0.f, 0.f, 0.f, 0.f);
      if (grow < N) v = *(const float4*)(A + (size_t)grow * K + kb + c4 * 4);
      As[c4 * 4 + 0][ar] = v.x;
      As[c4 * 4 + 1][ar] = v.y;
      As[c4 * 4 + 2][ar] = v.z;
      As[c4 * 4 + 3][ar] = v.w;
    }
#pragma unroll
    for (int q = 0; q < 2; ++q) {
      int c4 = wc4_0 + q;
      float4 v = *(const float4*)(W + (size_t)(kb + wk) * M + colbase + c4 * 4);
      *(float4*)&Ws[wk][c4 * 4] = v;
    }
    __syncthreads();

#pragma unroll
    for (int kk = 0; kk < KB; ++kk) {
      float4 a0 = *(const float4*)&As[kk][tr * 4];
      float4 a1 = *(const float4*)&As[kk][tr * 4 + 64];
      float4 w0 = *(const float4*)&Ws[kk][tc * 4];
      float4 w1 = *(const float4*)&Ws[kk][tc * 4 + 64];
      float a[8] = {a0.x, a0.y, a0.z, a0.w, a1.x, a1.y, a1.z, a1.w};
      float w[8] = {w0.x, w0.y, w0.z, w0.w, w1.x, w1.y, w1.z, w1.w};
#pragma unroll
      for (int i = 0; i < 8; ++i)
#pragma unroll
        for (int j = 0; j < 8; ++j) acc[i][j] = fmaf(a[i], w[j], acc[i][j]);
    }
    __syncthreads();
  }

#pragma unroll
  for (int i = 0; i < 8; ++i) {
    int r = rowbase + ((i < 4) ? (tr * 4 + i) : (64 + tr * 4 + (i - 4)));
    if (r >= N) continue;
#pragma unroll
    for (int jh = 0; jh < 2; ++jh) {
      int c = colbase + tc * 4 + jh * 64;
      float4 o;
      o.x = acc[i][jh * 4 + 0];
      o.y = acc[i][jh * 4 + 1];
      o.z = acc[i][jh * 4 + 2];
      o.w = acc[i][jh * 4 + 3];
      if (HAS_BIAS) {
        o.x += bias[c]; o.y += bias[c + 1]; o.z += bias[c + 2]; o.w += bias[c + 3];
      }
      if (RELU) {
        o.x = fmaxf(o.x, 0.f); o.y = fmaxf(o.y, 0.f);
        o.z = fmaxf(o.z, 0.f); o.w = fmaxf(o.w, 0.f);
      }
      *(float4*)(C + (size_t)r * M + c) = o;
    }
  }
}

// ---------------- mean pooling per graph (batch sorted) ----------------
__global__ void pool_k(const float* __restrict__ h, const int* __restrict__ batch,
                       float* __restrict__ pooled) {
  int g = blockIdx.x;
  int j = threadIdx.x;  // 128 threads = EMBD
  int lo = 0, hi = NODES;
  while (lo < hi) { int mid = (lo + hi) >> 1; if (batch[mid] < g) lo = mid + 1; else hi = mid; }
  int start = lo;
  int lo2 = start, hi2 = NODES;
  while (lo2 < hi2) { int mid = (lo2 + hi2) >> 1; if (batch[mid] < g + 1) lo2 = mid + 1; else hi2 = mid; }
  int end = lo2;
  float s = 0.f;
  for (int r = start; r < end; ++r) s += h[(size_t)r * EMBD + j];
  float c = (float)(end - start);
  pooled[g * EMBD + j] = s / fmaxf(c, 1.f);
}

// ---------------- head: logits = z2 @ Wc3[128,2] + bc3 ----------------
__global__ void head_k(const float* __restrict__ z2, const float* __restrict__ Wc3,
                       const float* __restrict__ bc3, float* __restrict__ out) {
  int wv = (blockIdx.x * blockDim.x + threadIdx.x) >> 6;
  int lane = threadIdx.x & 63;
  if (wv >= GRAPHS) return;
  float2 z = *(const float2*)(z2 + (size_t)wv * 128 + lane * 2);
  int j0 = lane * 2;
  float a0 = z.x * Wc3[j0 * 2 + 0] + z.y * Wc3[(j0 + 1) * 2 + 0];
  float a1 = z.x * Wc3[j0 * 2 + 1] + z.y * Wc3[(j0 + 1) * 2 + 1];
  for (int off = 32; off; off >>= 1) {
    a0 += __shfl_down(a0, off);
    a1 += __shfl_down(a1, off);
  }
  if (lane == 0) {
    out[wv * 2 + 0] = a0 + bc3[0];
    out[wv * 2 + 1] = a1 + bc3[1];
  }
}

extern "C" void kernel_launch(void* const* d_in, const int* in_sizes, int n_in,
                              void* d_out, int out_size, void* d_ws, size_t ws_size,
                              hipStream_t stream) {
  const float* x    = (const float*)d_in[0];
  const int*   ei   = (const int*)d_in[1];
  const int*   batch= (const int*)d_in[2];
  const float* W1 = (const float*)d_in[3];  const float* b1 = (const float*)d_in[4];
  const float* W2 = (const float*)d_in[5];  const float* b2 = (const float*)d_in[6];
  const float* W3 = (const float*)d_in[7];  const float* b3 = (const float*)d_in[8];
  const float* Wc1= (const float*)d_in[9];  const float* bc1= (const float*)d_in[10];
  const float* Wc2= (const float*)d_in[11]; const float* bc2= (const float*)d_in[12];
  const float* Wc3= (const float*)d_in[13]; const float* bc3= (const float*)d_in[14];
  float* out = (float*)d_out;

  char* ws = (char*)d_ws;
  size_t off = 0;
  auto alloc = [&](size_t bytes) -> void* {
    void* p = ws + off;
    off = (off + bytes + 255) & ~(size_t)255;
    return p;
  };
  f16*   F0      = (f16*)alloc((size_t)NODES * 256 * 2);
  f16*   F1      = (f16*)alloc((size_t)NODES * 256 * 2);
  float* R0      = (float*)alloc((size_t)NODES * 128 * 4);
  int*   csr_src = (int*)alloc((size_t)EDGES * 4);
  u32*   staging = (u32*)alloc((size_t)NB * CAP * 4);
  int*   row_ptr = (int*)alloc((size_t)(NODES + 1) * 4);
  float* dinv    = (float*)alloc((size_t)NODES * 4);
  int*   gcur    = (int*)alloc(NB * 4);
  int*   bbase   = (int*)alloc(NB * 4);
  f16*   Wt1     = (f16*)alloc((size_t)FIN * HIDDEN * 2);
  f16*   Wt2     = (f16*)alloc((size_t)HIDDEN * HIDDEN * 2);
  f16*   Wt3     = (f16*)alloc((size_t)HIDDEN * EMBD * 2);
  // fp32 overlays in F0 (dead after GEMM3 consumed it -> reused post-agg3)
  float* pooled = (float*)F0;
  float* z1     = pooled + (size_t)GRAPHS * EMBD;
  float* z2     = z1 + (size_t)GRAPHS * HIDDEN;

  const int* srcA = ei;
  const int* dstA = ei + EDGES;

  // ---- CSR build: two-phase LDS bin-sort (no per-edge global atomics) ----
  hipMemsetAsync(gcur, 0, NB * 4, stream);
  binA_k<<<(EDGES + TILE - 1) / TILE, 256, 0, stream>>>(srcA, dstA, staging, gcur);
  bscan_k<<<1, NB, 0, stream>>>(gcur, bbase);
  binB_k<<<NB, 512, 0, stream>>>(staging, gcur, bbase, row_ptr, dinv, csr_src);

  convw_k<<<(FIN * HIDDEN + 255) / 256, 256, 0, stream>>>(W1, Wt1, FIN, HIDDEN);
  convw_k<<<(HIDDEN * HIDDEN + 255) / 256, 256, 0, stream>>>(W2, Wt2, HIDDEN, HIDDEN);
  convw_k<<<(HIDDEN * EMBD + 255) / 256, 256, 0, stream>>>(W3, Wt3, HIDDEN, EMBD);
  prescale_k<<<(NODES * FIN / 4 + 255) / 256, 256, 0, stream>>>(x, dinv, F0);

  // 2 nodes per wave: 50000 waves -> 12500 blocks of 256
  const int aggBlocks = ((NODES + 1) / 2 * 64 + 255) / 256;
  const int gemmRows = (NODES + 127) / 128;        // 782

  // L1: AX = dinv*(sum xs) [128 f16]; H1s = dinv*relu(AX@W1+b1) [256 f16]
  agg_h<4, false><<<aggBlocks, 256, 0, stream>>>(F0, F1, row_ptr, csr_src, dinv, nullptr);
  gemm_h<FIN, true, true, true><<<dim3(gemmRows, 2), 256, 0, stream>>>(F1, Wt1, b1, dinv, F0, NODES, HIDDEN);
  // L2: AH1 = dinv*(sum H1s) [256 f16]; H2s = dinv*relu(AH1@W2+b2) [256 f16]
  agg_h<8, false><<<aggBlocks, 256, 0, stream>>>(F0, F1, row_ptr, csr_src, dinv, nullptr);
  gemm_h<HIDDEN, true, true, true><<<dim3(gemmRows, 2), 256, 0, stream>>>(F1, Wt2, b2, dinv, F0, NODES, HIDDEN);
  // L3: G3s = H2s@W3 [128 f16] (prescale carried through); H3 = dinv*(sum G3s)+b3 [128 f32]
  gemm_h<HIDDEN, false, false, false><<<dim3(gemmRows, 1), 256, 0, stream>>>(F0, Wt3, nullptr, nullptr, F1, NODES, EMBD);
  agg_h<4, true><<<aggBlocks, 256, 0, stream>>>(F1, R0, row_ptr, csr_src, dinv, b3);

  // pooling + MLP head (fp32)
  pool_k<<<GRAPHS, 128, 0, stream>>>(R0, batch, pooled);
  gemm_k<EMBD, true, true><<<dim3((GRAPHS + 127) / 128, 2), 256, 0, stream>>>(pooled, Wc1, bc1, z1, GRAPHS, HIDDEN);
  gemm_k<HIDDEN, true, true><<<dim3((GRAPHS + 127) / 128, 1), 256, 0, stream>>>(z1, Wc2, bc2, z2, GRAPHS, EMBD);
  head_k<<<GRAPHS / 4, 256, 0, stream>>>(z2, Wc3, bc3, out);
}

// Round 7
// 705.495 us; speedup vs baseline: 1.4332x; 1.0034x over previous
//
#include <hip/hip_runtime.h>
#include <cstdint>
#include <cstddef>

#define NODES  100000
#define EDGES  3200000
#define FIN    128
#define HIDDEN 256
#define EMBD   128
#define GRAPHS 2048

// bucket bin-sort geometry
#define NB   256            // buckets
#define NPB  391            // nodes per bucket (ceil(100000/256))
#define CAP  16384          // staging capacity per bucket (exp ~12.5K, 30+ sigma slack)
#define TILE 4096           // edges per phase-A block

typedef _Float16 f16;
typedef f16 f16x2 __attribute__((ext_vector_type(2)));
typedef f16 f16x4 __attribute__((ext_vector_type(4)));
typedef f16 f16x8 __attribute__((ext_vector_type(8)));
typedef float f32x4 __attribute__((ext_vector_type(4)));
typedef unsigned int u32;

// ---------------- Phase A: bin edges by dst-bucket into staging ----------------
// staging word = (src << 9) | (dst - bucket*NPB);  src<2^17, local<391<2^9
__global__ __launch_bounds__(256) void binA_k(const int* __restrict__ src,
                                              const int* __restrict__ dst,
                                              u32* __restrict__ staging,
                                              int* __restrict__ gcur) {
  __shared__ u32 buf[TILE];
  __shared__ int bcnt[NB], bsh[NB], bstart[NB], bcur[NB], gbase[NB];
  const int tid = threadIdx.x;
  const int tb = blockIdx.x * TILE;

  bcnt[tid] = 0;
  __syncthreads();

  // pass 1: count per bucket
#pragma unroll
  for (int j = 0; j < TILE / 256; ++j) {
    int i = tb + j * 256 + tid;
    if (i < EDGES) atomicAdd(&bcnt[dst[i] / NPB], 1);
  }
  __syncthreads();

  // inclusive scan of counts (Hillis-Steele over 256)
  bsh[tid] = bcnt[tid];
  __syncthreads();
  for (int off = 1; off < NB; off <<= 1) {
    int t = (tid >= off) ? bsh[tid - off] : 0;
    __syncthreads();
    bsh[tid] += t;
    __syncthreads();
  }
  bstart[tid] = bsh[tid] - bcnt[tid];
  bcur[tid] = bsh[tid] - bcnt[tid];
  __syncthreads();

  // pass 2: scatter packed words into bucket-ordered LDS
#pragma unroll
  for (int j = 0; j < TILE / 256; ++j) {
    int i = tb + j * 256 + tid;
    if (i < EDGES) {
      int d = dst[i];
      int b = d / NPB;
      u32 w = ((u32)src[i] << 9) | (u32)(d - b * NPB);
      buf[atomicAdd(&bcur[b], 1)] = w;
    }
  }
  // reserve global ranges (256 atomics per tile)
  gbase[tid] = atomicAdd(&gcur[tid], bcnt[tid]);
  __syncthreads();

  // copy-out: thread t owns bucket t; consecutive stores -> dense lines
  {
    int c = bcnt[tid], st = bstart[tid];
    u32* outp = staging + (size_t)tid * CAP + gbase[tid];
    for (int k = 0; k < c; ++k) outp[k] = buf[st + k];
  }
}

// ---------------- bucket-base exclusive scan (1 block) ----------------
__global__ void bscan_k(const int* __restrict__ gcur, int* __restrict__ bbase) {
  __shared__ int sh[NB];
  int tid = threadIdx.x;
  int v = gcur[tid];
  sh[tid] = v;
  __syncthreads();
  for (int off = 1; off < NB; off <<= 1) {
    int t = (tid >= off) ? sh[tid - off] : 0;
    __syncthreads();
    sh[tid] += t;
    __syncthreads();
  }
  bbase[tid] = sh[tid] - v;  // exclusive
}

// ---------------- Phase B: per-bucket CSR finalize (row_ptr, dinv, csr_src) ----------------
__global__ __launch_bounds__(512) void binB_k(const u32* __restrict__ staging,
                                              const int* __restrict__ gcur,
                                              const int* __restrict__ bbase,
                                              int* __restrict__ row_ptr,
                                              float* __restrict__ dinv,
                                              int* __restrict__ csr_src) {
  __shared__ int ncnt[512];
  __shared__ int ncur[512];
  const int b = blockIdx.x;
  const int tid = threadIdx.x;
  const int m = gcur[b];
  const int base = bbase[b];
  const int nb0 = b * NPB;
  const int nn = min(NPB, NODES - nb0);
  const u32* sb = staging + (size_t)b * CAP;

  ncnt[tid] = 0;
  __syncthreads();

  // count per local node
  for (int k = tid; k < m; k += 512) atomicAdd(&ncnt[sb[k] & 511], 1);
  __syncthreads();

  int v = ncnt[tid];
  // in-place inclusive scan over 512
  for (int off = 1; off < 512; off <<= 1) {
    int t = (tid >= off) ? ncnt[tid - off] : 0;
    __syncthreads();
    ncnt[tid] += t;
    __syncthreads();
  }
  int incl = ncnt[tid];
  if (tid < nn) {
    row_ptr[nb0 + tid + 1] = base + incl;
    dinv[nb0 + tid] = rsqrtf((float)(v + 1));
    ncur[tid] = base + incl - v;  // global cursor start (exclusive)
  }
  if (b == 0 && tid == 0) row_ptr[0] = 0;
  __syncthreads();

  // scatter src into block-owned contiguous csr region (dense writes)
  for (int k = tid; k < m; k += 512) {
    u32 w = sb[k];
    int pos = atomicAdd(&ncur[w & 511], 1);
    csr_src[pos] = (int)(w >> 9);
  }
}

// ---------------- prescale: xs[i] = f16(dinv[i] * x[i]) ----------------
__global__ void prescale_k(const float* __restrict__ x, const float* __restrict__ dinv,
                           f16* __restrict__ xs) {
  int idx = blockIdx.x * blockDim.x + threadIdx.x;  // over NODES*FIN/4
  if (idx >= NODES * FIN / 4) return;
  int row = idx >> 5;  // FIN/4 = 32 float4 per row
  float4 v = *(const float4*)(x + (size_t)idx * 4);
  float d = dinv[row];
  f16x4 o = {(f16)(d * v.x), (f16)(d * v.y), (f16)(d * v.z), (f16)(d * v.w)};
  *(f16x4*)(xs + (size_t)idx * 4) = o;
}

// ---------------- fused weight convert+transpose for W1,W2,W3 ----------------
__global__ void convw3_k(const float* __restrict__ W1, const float* __restrict__ W2,
                         const float* __restrict__ W3, f16* __restrict__ Wt1,
                         f16* __restrict__ Wt2, f16* __restrict__ Wt3) {
  int i = blockIdx.x * blockDim.x + threadIdx.x;
  // W1: 128x256 (32768), W2: 256x256 (65536), W3: 256x128 (32768)
  if (i < 32768) {
    int k = i >> 8, m = i & 255;
    Wt1[(size_t)m * FIN + k] = (f16)W1[i];
  } else if (i < 98304) {
    int j = i - 32768;
    int k = j >> 8, m = j & 255;
    Wt2[(size_t)m * HIDDEN + k] = (f16)W2[j];
  } else if (i < 131072) {
    int j = i - 98304;
    int k = j >> 7, m = j & 127;
    Wt3[(size_t)m * HIDDEN + k] = (f16)W3[j];
  }
}

// ---------------- aggregation (f16 in, fp32 accum) ----------------
// 2 nodes per wave (32 lanes x V f16 each); U=8 gathers in flight per node stream.
// in is dinv-prescaled: out[i] = dinv[i] * (sum_{s in N(i)} in[s] + in[i]) (+bias, FINAL->fp32)
template <int V, bool FINAL>
__global__ __launch_bounds__(256) void agg_h(const f16* __restrict__ in, void* __restrict__ outv,
                      const int* __restrict__ row_ptr, const int* __restrict__ csr_src,
                      const float* __restrict__ dinv, const float* __restrict__ bias) {
  constexpr int D = V * 32;   // row width in f16
  constexpr int U = 8;        // gathers in flight per node stream (16/wave)
  const int wid = (blockIdx.x * blockDim.x + threadIdx.x) >> 6;
  const int half = (threadIdx.x >> 5) & 1;
  const int lane = threadIdx.x & 31;
  const int node = wid * 2 + half;
  if (node >= NODES) return;
  const int c0 = lane * V;
  const f16* __restrict__ inc = in + c0;

  float acc[V];
#pragma unroll
  for (int v = 0; v < V; ++v) acc[v] = 0.f;

  const int beg = row_ptr[node], end = row_ptr[node + 1];
  int k = beg;
  if constexpr (V == 8) {
    for (; k + U <= end; k += U) {
      int s[U];
#pragma unroll
      for (int u = 0; u < U; ++u) s[u] = csr_src[k + u];
      f16x8 hv[U];
#pragma unroll
      for (int u = 0; u < U; ++u) hv[u] = *(const f16x8*)(inc + (size_t)s[u] * D);
#pragma unroll
      for (int u = 0; u < U; ++u)
#pragma unroll
        for (int v = 0; v < V; ++v) acc[v] += (float)hv[u][v];
    }
    for (; k < end; ++k) {
      f16x8 hv = *(const f16x8*)(inc + (size_t)csr_src[k] * D);
#pragma unroll
      for (int v = 0; v < V; ++v) acc[v] += (float)hv[v];
    }
    f16x8 hv = *(const f16x8*)(inc + (size_t)node * D);  // self loop
#pragma unroll
    for (int v = 0; v < V; ++v) acc[v] += (float)hv[v];
  } else {
    for (; k + U <= end; k += U) {
      int s[U];
#pragma unroll
      for (int u = 0; u < U; ++u) s[u] = csr_src[k + u];
      f16x4 hv[U];
#pragma unroll
      for (int u = 0; u < U; ++u) hv[u] = *(const f16x4*)(inc + (size_t)s[u] * D);
#pragma unroll
      for (int u = 0; u < U; ++u)
#pragma unroll
        for (int v = 0; v < V; ++v) acc[v] += (float)hv[u][v];
    }
    for (; k < end; ++k) {
      f16x4 hv = *(const f16x4*)(inc + (size_t)csr_src[k] * D);
#pragma unroll
      for (int v = 0; v < V; ++v) acc[v] += (float)hv[v];
    }
    f16x4 hv = *(const f16x4*)(inc + (size_t)node * D);  // self loop
#pragma unroll
    for (int v = 0; v < V; ++v) acc[v] += (float)hv[v];
  }

  const float di = dinv[node];
  if constexpr (FINAL) {  // V==4 path, fp32 out + bias
    float* out = (float*)outv;
    float4 o = {di * acc[0] + bias[c0], di * acc[1] + bias[c0 + 1],
                di * acc[2] + bias[c0 + 2], di * acc[3] + bias[c0 + 3]};
    *(float4*)(out + (size_t)node * D + c0) = o;
  } else {
    f16* out = (f16*)outv;
    if constexpr (V == 8) {
      f16x8 o;
#pragma unroll
      for (int v = 0; v < V; ++v) o[v] = (f16)(di * acc[v]);
      *(f16x8*)(out + (size_t)node * D + c0) = o;
    } else {
      f16x4 o;
#pragma unroll
      for (int v = 0; v < V; ++v) o[v] = (f16)(di * acc[v]);
      *(f16x4*)(out + (size_t)node * D + c0) = o;
    }
  }
}

// ---------------- wide f16 MFMA GEMM: C[N,256] = dinv*relu(A[N,K]@W[K,256]+b) ----------------
// Tile 128x256, 4 waves, each wave 64x128 (4x8 fragments): 12 ds_read_b128 feed
// 32 MFMAs per K-step (vs 8:16 in the square kernel) -> LDS no longer the bound.
template <int K>
__global__ __launch_bounds__(256, 2) void gemm_w(const f16* __restrict__ A,
                                                 const f16* __restrict__ Wt,
                                                 const float* __restrict__ bias,
                                                 const float* __restrict__ dinv,
                                                 f16* __restrict__ C, int N) {
  constexpr int M = 256;
  __shared__ f16 As[128][40];  // [row][k], pad 40 halves: 2-way max aliasing
  __shared__ f16 Bs[256][40];  // [col][k]

  const int tid = threadIdx.x;
  const int rowbase = blockIdx.x * 128;
  const int l = tid & 63;
  const int wv = tid >> 6;
  const int wr = (wv >> 1) * 64;   // 0 / 64
  const int wc = (wv & 1) * 128;   // 0 / 128
  const int lr = tid >> 1;         // A-stage row 0..127
  const int lc = (tid & 1) * 16;   // A-stage k-offset

  f32x4 acc[4][8];
#pragma unroll
  for (int i = 0; i < 4; ++i)
#pragma unroll
    for (int j = 0; j < 8; ++j) acc[i][j] = (f32x4){0.f, 0.f, 0.f, 0.f};

  const int arow = min(rowbase + lr, N - 1);  // clamp: OOB rows read row N-1, never stored
  const f16* aptr = A + (size_t)arow * K + lc;
  const f16* bptr = Wt + (size_t)tid * K;     // B-stage: thread = col 0..255

  for (int kb = 0; kb < K; kb += 32) {
    *(f16x8*)&As[lr][lc]     = *(const f16x8*)(aptr + kb);
    *(f16x8*)&As[lr][lc + 8] = *(const f16x8*)(aptr + kb + 8);
#pragma unroll
    for (int q = 0; q < 4; ++q)
      *(f16x8*)&Bs[tid][q * 8] = *(const f16x8*)(bptr + kb + q * 8);
    __syncthreads();

    f16x8 a[4], b[8];
#pragma unroll
    for (int f = 0; f < 4; ++f)
      a[f] = *(const f16x8*)&As[wr + f * 16 + (l & 15)][(l >> 4) * 8];
#pragma unroll
    for (int g = 0; g < 8; ++g)
      b[g] = *(const f16x8*)&Bs[wc + g * 16 + (l & 15)][(l >> 4) * 8];
#pragma unroll
    for (int fm = 0; fm < 4; ++fm)
#pragma unroll
      for (int g = 0; g < 8; ++g)
        acc[fm][g] = __builtin_amdgcn_mfma_f32_16x16x32_f16(a[fm], b[g], acc[fm][g], 0, 0, 0);
    __syncthreads();
  }

  float bv[8];
#pragma unroll
  for (int g = 0; g < 8; ++g) bv[g] = bias[wc + g * 16 + (l & 15)];

#pragma unroll
  for (int fm = 0; fm < 4; ++fm) {
#pragma unroll
    for (int r = 0; r < 4; ++r) {
      int row = rowbase + wr + fm * 16 + (l >> 4) * 4 + r;
      if (row >= N) continue;
      float dv = dinv[row];
#pragma unroll
      for (int g = 0; g < 8; ++g) {
        int col = wc + g * 16 + (l & 15);
        float v = fmaxf(acc[fm][g][r] + bv[g], 0.f);
        C[(size_t)row * M + col] = (f16)(v * dv);
      }
    }
  }
}

// ---------------- square f16 MFMA GEMM (for the 256->128 layer) ----------------
template <int K, bool RELU, bool BIAS, bool DSCALE>
__global__ __launch_bounds__(256) void gemm_h(const f16* __restrict__ A,
                                              const f16* __restrict__ Wt,
                                              const float* __restrict__ bias,
                                              const float* __restrict__ dinv,
                                              f16* __restrict__ C, int N, int M) {
  __shared__ f16 As[128][40];  // [row][k], pad to 40 halves (80B) for bank spread
  __shared__ f16 Bs[128][40];  // [col][k]

  const int tid = threadIdx.x;
  const int rowbase = blockIdx.x * 128;
  const int colbase = blockIdx.y * 128;
  const int l = tid & 63;
  const int wr = ((tid >> 6) >> 1) * 64;  // wave row offset 0/64
  const int wc = ((tid >> 6) & 1) * 64;   // wave col offset 0/64
  const int lr = tid >> 1;                // 0..127: tile row (A) / tile col (B)
  const int lc = (tid & 1) * 16;          // half-offset within BK=32

  f32x4 acc[4][4];
#pragma unroll
  for (int i = 0; i < 4; ++i)
#pragma unroll
    for (int j = 0; j < 4; ++j) acc[i][j] = (f32x4){0.f, 0.f, 0.f, 0.f};

  const int arow = min(rowbase + lr, N - 1);  // clamp: OOB rows read row N-1, never stored
  const f16* aptr = A + (size_t)arow * K + lc;
  const f16* bptr = Wt + (size_t)(colbase + lr) * K + lc;

  for (int kb = 0; kb < K; kb += 32) {
    *(f16x8*)&As[lr][lc]     = *(const f16x8*)(aptr + kb);
    *(f16x8*)&As[lr][lc + 8] = *(const f16x8*)(aptr + kb + 8);
    *(f16x8*)&Bs[lr][lc]     = *(const f16x8*)(bptr + kb);
    *(f16x8*)&Bs[lr][lc + 8] = *(const f16x8*)(bptr + kb + 8);
    __syncthreads();

    f16x8 a[4], b[4];
#pragma unroll
    for (int f = 0; f < 4; ++f) {
      a[f] = *(const f16x8*)&As[wr + f * 16 + (l & 15)][(l >> 4) * 8];
      b[f] = *(const f16x8*)&Bs[wc + f * 16 + (l & 15)][(l >> 4) * 8];
    }
#pragma unroll
    for (int fm = 0; fm < 4; ++fm)
#pragma unroll
      for (int fn = 0; fn < 4; ++fn)
        acc[fm][fn] = __builtin_amdgcn_mfma_f32_16x16x32_f16(a[fm], b[fn], acc[fm][fn], 0, 0, 0);
    __syncthreads();
  }

  float bv[4];
#pragma unroll
  for (int fn = 0; fn < 4; ++fn)
    bv[fn] = BIAS ? bias[colbase + wc + fn * 16 + (l & 15)] : 0.f;

#pragma unroll
  for (int fm = 0; fm < 4; ++fm) {
#pragma unroll
    for (int r = 0; r < 4; ++r) {
      int row = rowbase + wr + fm * 16 + (l >> 4) * 4 + r;
      if (row >= N) continue;
      float dv = DSCALE ? dinv[row] : 1.f;
#pragma unroll
      for (int fn = 0; fn < 4; ++fn) {
        int col = colbase + wc + fn * 16 + (l & 15);
        float v = acc[fm][fn][r] + bv[fn];
        if (RELU) v = fmaxf(v, 0.f);
        C[(size_t)row * M + col] = (f16)(v * dv);
      }
    }
  }
}

// ---------------- fp32 GEMM for the tiny head (N=2048) ----------------
template <int K, bool RELU, bool HAS_BIAS>
__global__ __launch_bounds__(256) void gemm_k(const float* __restrict__ A,
                                              const float* __restrict__ W,
                                              const float* __restrict__ bias,
                                              float* __restrict__ C, int N, int M) {
  constexpr int KB = 16;
  __shared__ float As[KB][128];
  __shared__ float Ws[KB][128];

  const int tid = threadIdx.x;
  const int rowbase = blockIdx.x * 128;
  const int colbase = blockIdx.y * 128;
  const int tr = tid >> 4;
  const int tc = tid & 15;
  const int ar = tid >> 1;
  const int ac4_0 = (tid & 1) * 2;
  const int wk = tid >> 4;
  const int wc4_0 = (tid & 15) * 2;

  float acc[8][8];
#pragma unroll
  for (int i = 0; i < 8; ++i)
#pragma unroll
    for (int j = 0; j < 8; ++j) acc[i][j] = 0.f;

  for (int kb = 0; kb < K; kb += KB) {
#pragma unroll
    for (int q = 0; q < 2; ++q) {
      int c4 = ac4_0 + q;
      int grow = rowbase + ar;
      float4 v = make_float4(0.f, 0.f, 0.f, 0.f);
      if (grow < N) v = *(const float4*)(A + (size_t)grow * K + kb + c4 * 4);
      As[c4 * 4 + 0][ar] = v.x;
      As[c4 * 4 + 1][ar] = v.y;
      As[c4 * 4 + 2][ar] = v.z;
      As[c4 * 4 + 3][ar] = v.w;
    }
#pragma unroll
    for (int q = 0; q < 2; ++q) {
      int c4 = wc4_0 + q;
      float4 v = *(const float4*)(W + (size_t)(kb + wk) * M + colbase + c4 * 4);
      *(float4*)&Ws[wk][c4 * 4] = v;
    }
    __syncthreads();

#pragma unroll
    for (int kk = 0; kk < KB; ++kk) {
      float4 a0 = *(const float4*)&As[kk][tr * 4];
      float4 a1 = *(const float4*)&As[kk][tr * 4 + 64];
      float4 w0 = *(const float4*)&Ws[kk][tc * 4];
      float4 w1 = *(const float4*)&Ws[kk][tc * 4 + 64];
      float a[8] = {a0.x, a0.y, a0.z, a0.w, a1.x, a1.y, a1.z, a1.w};
      float w[8] = {w0.x, w0.y, w0.z, w0.w, w1.x, w1.y, w1.z, w1.w};
#pragma unroll
      for (int i = 0; i < 8; ++i)
#pragma unroll
        for (int j = 0; j < 8; ++j) acc[i][j] = fmaf(a[i], w[j], acc[i][j]);
    }
    __syncthreads();
  }

#pragma unroll
  for (int i = 0; i < 8; ++i) {
    int r = rowbase + ((i < 4) ? (tr * 4 + i) : (64 + tr * 4 + (i - 4)));
    if (r >= N) continue;
#pragma unroll
    for (int jh = 0; jh < 2; ++jh) {
      int c = colbase + tc * 4 + jh * 64;
      float4 o;
      o.x = acc[i][jh * 4 + 0];
      o.y = acc[i][jh * 4 + 1];
      o.z = acc[i][jh * 4 + 2];
      o.w = acc[i][jh * 4 + 3];
      if (HAS_BIAS) {
        o.x += bias[c]; o.y += bias[c + 1]; o.z += bias[c + 2]; o.w += bias[c + 3];
      }
      if (RELU) {
        o.x = fmaxf(o.x, 0.f); o.y = fmaxf(o.y, 0.f);
        o.z = fmaxf(o.z, 0.f); o.w = fmaxf(o.w, 0.f);
      }
      *(float4*)(C + (size_t)r * M + c) = o;
    }
  }
}

// ---------------- mean pooling per graph (batch sorted) ----------------
__global__ void pool_k(const float* __restrict__ h, const int* __restrict__ batch,
                       float* __restrict__ pooled) {
  int g = blockIdx.x;
  int j = threadIdx.x;  // 128 threads = EMBD
  int lo = 0, hi = NODES;
  while (lo < hi) { int mid = (lo + hi) >> 1; if (batch[mid] < g) lo = mid + 1; else hi = mid; }
  int start = lo;
  int lo2 = start, hi2 = NODES;
  while (lo2 < hi2) { int mid = (lo2 + hi2) >> 1; if (batch[mid] < g + 1) lo2 = mid + 1; else hi2 = mid; }
  int end = lo2;
  float s = 0.f;
  for (int r = start; r < end; ++r) s += h[(size_t)r * EMBD + j];
  float c = (float)(end - start);
  pooled[g * EMBD + j] = s / fmaxf(c, 1.f);
}

// ---------------- head: logits = z2 @ Wc3[128,2] + bc3 ----------------
__global__ void head_k(const float* __restrict__ z2, const float* __restrict__ Wc3,
                       const float* __restrict__ bc3, float* __restrict__ out) {
  int wv = (blockIdx.x * blockDim.x + threadIdx.x) >> 6;
  int lane = threadIdx.x & 63;
  if (wv >= GRAPHS) return;
  float2 z = *(const float2*)(z2 + (size_t)wv * 128 + lane * 2);
  int j0 = lane * 2;
  float a0 = z.x * Wc3[j0 * 2 + 0] + z.y * Wc3[(j0 + 1) * 2 + 0];
  float a1 = z.x * Wc3[j0 * 2 + 1] + z.y * Wc3[(j0 + 1) * 2 + 1];
  for (int off = 32; off; off >>= 1) {
    a0 += __shfl_down(a0, off);
    a1 += __shfl_down(a1, off);
  }
  if (lane == 0) {
    out[wv * 2 + 0] = a0 + bc3[0];
    out[wv * 2 + 1] = a1 + bc3[1];
  }
}

extern "C" void kernel_launch(void* const* d_in, const int* in_sizes, int n_in,
                              void* d_out, int out_size, void* d_ws, size_t ws_size,
                              hipStream_t stream) {
  const float* x    = (const float*)d_in[0];
  const int*   ei   = (const int*)d_in[1];
  const int*   batch= (const int*)d_in[2];
  const float* W1 = (const float*)d_in[3];  const float* b1 = (const float*)d_in[4];
  const float* W2 = (const float*)d_in[5];  const float* b2 = (const float*)d_in[6];
  const float* W3 = (const float*)d_in[7];  const float* b3 = (const float*)d_in[8];
  const float* Wc1= (const float*)d_in[9];  const float* bc1= (const float*)d_in[10];
  const float* Wc2= (const float*)d_in[11]; const float* bc2= (const float*)d_in[12];
  const float* Wc3= (const float*)d_in[13]; const float* bc3= (const float*)d_in[14];
  float* out = (float*)d_out;

  char* ws = (char*)d_ws;
  size_t off = 0;
  auto alloc = [&](size_t bytes) -> void* {
    void* p = ws + off;
    off = (off + bytes + 255) & ~(size_t)255;
    return p;
  };
  f16*   F0      = (f16*)alloc((size_t)NODES * 256 * 2);
  f16*   F1      = (f16*)alloc((size_t)NODES * 256 * 2);
  float* R0      = (float*)alloc((size_t)NODES * 128 * 4);
  int*   csr_src = (int*)alloc((size_t)EDGES * 4);
  u32*   staging = (u32*)alloc((size_t)NB * CAP * 4);
  int*   row_ptr = (int*)alloc((size_t)(NODES + 1) * 4);
  float* dinv    = (float*)alloc((size_t)NODES * 4);
  int*   gcur    = (int*)alloc(NB * 4);
  int*   bbase   = (int*)alloc(NB * 4);
  f16*   Wt1     = (f16*)alloc((size_t)FIN * HIDDEN * 2);
  f16*   Wt2     = (f16*)alloc((size_t)HIDDEN * HIDDEN * 2);
  f16*   Wt3     = (f16*)alloc((size_t)HIDDEN * EMBD * 2);
  // fp32 overlays in F0 (dead after GEMM3 consumed it -> reused post-agg3)
  float* pooled = (float*)F0;
  float* z1     = pooled + (size_t)GRAPHS * EMBD;
  float* z2     = z1 + (size_t)GRAPHS * HIDDEN;

  const int* srcA = ei;
  const int* dstA = ei + EDGES;

  // ---- CSR build: two-phase LDS bin-sort (no per-edge global atomics) ----
  hipMemsetAsync(gcur, 0, NB * 4, stream);
  binA_k<<<(EDGES + TILE - 1) / TILE, 256, 0, stream>>>(srcA, dstA, staging, gcur);
  bscan_k<<<1, NB, 0, stream>>>(gcur, bbase);
  binB_k<<<NB, 512, 0, stream>>>(staging, gcur, bbase, row_ptr, dinv, csr_src);

  convw3_k<<<(131072 + 255) / 256, 256, 0, stream>>>(W1, W2, W3, Wt1, Wt2, Wt3);
  prescale_k<<<(NODES * FIN / 4 + 255) / 256, 256, 0, stream>>>(x, dinv, F0);

  // 2 nodes per wave: 50000 waves -> 12500 blocks of 256
  const int aggBlocks = ((NODES + 1) / 2 * 64 + 255) / 256;
  const int gemmRows = (NODES + 127) / 128;        // 782

  // L1: AX = dinv*(sum xs) [128 f16]; H1s = dinv*relu(AX@W1+b1) [256 f16]
  agg_h<4, false><<<aggBlocks, 256, 0, stream>>>(F0, F1, row_ptr, csr_src, dinv, nullptr);
  gemm_w<FIN><<<gemmRows, 256, 0, stream>>>(F1, Wt1, b1, dinv, F0, NODES);
  // L2: AH1 = dinv*(sum H1s) [256 f16]; H2s = dinv*relu(AH1@W2+b2) [256 f16]
  agg_h<8, false><<<aggBlocks, 256, 0, stream>>>(F0, F1, row_ptr, csr_src, dinv, nullptr);
  gemm_w<HIDDEN><<<gemmRows, 256, 0, stream>>>(F1, Wt2, b2, dinv, F0, NODES);
  // L3: G3s = H2s@W3 [128 f16] (prescale carried through); H3 = dinv*(sum G3s)+b3 [128 f32]
  gemm_h<HIDDEN, false, false, false><<<dim3(gemmRows, 1), 256, 0, stream>>>(F0, Wt3, nullptr, nullptr, F1, NODES, EMBD);
  agg_h<4, true><<<aggBlocks, 256, 0, stream>>>(F1, R0, row_ptr, csr_src, dinv, b3);

  // pooling + MLP head (fp32)
  pool_k<<<GRAPHS, 128, 0, stream>>>(R0, batch, pooled);
  gemm_k<EMBD, true, true><<<dim3((GRAPHS + 127) / 128, 2), 256, 0, stream>>>(pooled, Wc1, bc1, z1, GRAPHS, HIDDEN);
  gemm_k<HIDDEN, true, true><<<dim3((GRAPHS + 127) / 128, 1), 256, 0, stream>>>(z1, Wc2, bc2, z2, GRAPHS, EMBD);
  head_k<<<GRAPHS / 4, 256, 0, stream>>>(z2, Wc3, bc3, out);
}